// Round 12
// baseline (390.202 us; speedup 1.0000x reference)
//
#include <hip/hip_runtime.h>
#include <hip/hip_bf16.h>
#include <math.h>

#define N_NODES 20000
#define N_EDGES 320000

#define INV1   0.31622776601683794f   // 1/sqrt(10)
#define SC2    0.1f                   // 1/sqrt(100)
#define IS3    0.5773502691896258f    // 1/sqrt(3)
#define C_S    0.3826834323650898f    // sin(pi/8)
#define C_X    0.9238795325112867f    // cos(pi/8)
#define INV64  0.125f                 // 1/sqrt(64)
#define INVLO  0.08838834764831845f   // 1/sqrt(128)

typedef short     short8 __attribute__((ext_vector_type(8)));
typedef float     f32x4  __attribute__((ext_vector_type(4)));

// fast silu: x * rcp(1 + exp2(-x*log2(e))) — verified passing (round 3).
__device__ __forceinline__ float silu_f(float x) {
    float e = __builtin_amdgcn_exp2f(-1.44269504088896f * x);
    return x * __builtin_amdgcn_rcpf(1.0f + e);
}
// software RNE f32->bf16 (verified). NOTE: v_cvt_pk_bf16_f32 inline asm
// produced NaN garbage on this toolchain (round 1/2) — do not reintroduce.
// NOTE (round 10): fp8-e4m3 ew interface fails absmax (0.094 > 0.085) —
// interface must stay bf16.
__device__ __forceinline__ unsigned short f2bf(float x) {
    __hip_bfloat16 h = __float2bfloat16(x);
    return *reinterpret_cast<unsigned short*>(&h);
}
__device__ __forceinline__ float bf2f(unsigned short u) {
    __hip_bfloat16 h;
    *reinterpret_cast<unsigned short*>(&h) = u;
    return __bfloat162float(h);
}

// ---------------- A: hist + weight prep ------------------------------------
// blocks [0, 1250): edge-dst histogram
// blocks [1250, 1394): W2/W1 bf16 transpose prep
__global__ __launch_bounds__(256) void k_prep2(
    const int* __restrict__ edst, int* __restrict__ hist,
    const float* __restrict__ W2, const float* __restrict__ W1,
    unsigned short* __restrict__ w2t, unsigned short* __restrict__ w1t)
{
    if (blockIdx.x < N_EDGES / 256) {
        const int e = blockIdx.x * 256 + threadIdx.x;
        atomicAdd(&hist[edst[e]], 1);
    } else {
        const int i = (blockIdx.x - N_EDGES / 256) * 256 + threadIdx.x;
        if (i < 32768) {
            const int n = i >> 7, k = i & 127;
            w2t[i] = (k < 100) ? f2bf(W2[k*256 + n] * SC2) : (unsigned short)0;
        } else if (i < 32768 + 3584) {
            const int j = i - 32768;
            const int n = j >> 5, k = j & 31;
            w1t[j] = (k < 10 && n < 100) ? f2bf(W1[k*100 + n] * INV1)
                                         : (unsigned short)0;
        }
    }
}

__global__ __launch_bounds__(1024) void k_scan(const int* __restrict__ hist,
                                               int* __restrict__ starts,
                                               int* __restrict__ cursor) {
    __shared__ int part[1024];
    const int t = threadIdx.x;
    const int C = 20;
    const int base = t * C;
    int s = 0;
    for (int i = 0; i < C; ++i) {
        const int idx = base + i;
        if (idx < N_NODES) s += hist[idx];
    }
    part[t] = s;
    __syncthreads();
    for (int off = 1; off < 1024; off <<= 1) {
        int v = (t >= off) ? part[t - off] : 0;
        __syncthreads();
        part[t] += v;
        __syncthreads();
    }
    int run = part[t] - s;
    for (int i = 0; i < C; ++i) {
        const int idx = base + i;
        if (idx < N_NODES) {
            starts[idx] = run;
            cursor[idx] = run;
            run += hist[idx];
        }
    }
    if (t == 1023) starts[N_NODES] = N_EDGES;
}

// ---------------- C: merged mid — scatter || edge-MLP || node_in ------------
// Round-12: third merge. All three are mutually independent once scan is
// done; co-residency overlaps their latency streams (R11-validated lever):
//   blocks [0, 1250):     scatter — sort esrc/eattr/eidx by dst
//   blocks [1250, 3750):  MLP     — R9-verbatim MFMA pipeline (elen f32)
//   blocks [3750, 8750):  node_in — fvb + out = c_s*m (raw aliases Hs LDS)
#define SCAT_B (N_EDGES / 256)
#define MLP_B  (N_EDGES / 128)
#define NODE_B (N_NODES / 4)

// load one edge's elen slice as bf16 short8: lane-q covers elems q*8..q*8+7;
// row is 10 floats, so q=1 has elems 8,9 valid + 6 zeros.
__device__ __forceinline__ short8 ld_elen8(const float* __restrict__ elen,
                                           int e, int q)
{
    const float* er = elen + (size_t)e * 10 + q * 8;
    float v0 = er[0], v1 = er[1];
    float v2 = 0.f, v3 = 0.f, v4 = 0.f, v5 = 0.f, v6 = 0.f, v7 = 0.f;
    if (q == 0) {
        v2 = er[2]; v3 = er[3]; v4 = er[4];
        v5 = er[5]; v6 = er[6]; v7 = er[7];
    }
    short8 r;
    r[0] = (short)f2bf(v0); r[1] = (short)f2bf(v1);
    r[2] = (short)f2bf(v2); r[3] = (short)f2bf(v3);
    r[4] = (short)f2bf(v4); r[5] = (short)f2bf(v5);
    r[6] = (short)f2bf(v6); r[7] = (short)f2bf(v7);
    return r;
}

__device__ __forceinline__ void p2_ldB(const unsigned short* __restrict__ w2t,
                                       int ntA, int m15, int q,
                                       short8* BA, short8* BB)
{
    const unsigned short* bpA = w2t + ((size_t)(ntA*16 + m15) << 7);
    const unsigned short* bpB = w2t + ((size_t)((ntA + 4)*16 + m15) << 7);
    #pragma unroll
    for (int s = 0; s < 4; ++s) {
        BA[s] = *(const short8*)(bpA + s*32 + q*8);
        BB[s] = *(const short8*)(bpB + s*32 + q*8);
    }
}

__device__ __forceinline__ void p2_mfma_store(
    const short8* A0, const short8* A1,
    const short8* BA, const short8* BB,
    unsigned int* __restrict__ dstp,
    int e0, int eb, int m15, int q, int nt4)
{
    f32x4 ca0 = {0.f,0.f,0.f,0.f}, ca1 = {0.f,0.f,0.f,0.f};
    f32x4 cb0 = {0.f,0.f,0.f,0.f}, cb1 = {0.f,0.f,0.f,0.f};
    #pragma unroll
    for (int s = 0; s < 4; ++s) {
        ca0 = __builtin_amdgcn_mfma_f32_16x16x32_bf16(BA[s], A0[s], ca0, 0, 0, 0);
        ca1 = __builtin_amdgcn_mfma_f32_16x16x32_bf16(BA[s], A1[s], ca1, 0, 0, 0);
        cb0 = __builtin_amdgcn_mfma_f32_16x16x32_bf16(BB[s], A0[s], cb0, 0, 0, 0);
        cb1 = __builtin_amdgcn_mfma_f32_16x16x32_bf16(BB[s], A1[s], cb1, 0, 0, 0);
    }
    uint4 U0, U1;
    U0.x = (unsigned int)f2bf(ca0[0]) | ((unsigned int)f2bf(cb0[0]) << 16);
    U0.y = (unsigned int)f2bf(ca0[1]) | ((unsigned int)f2bf(cb0[1]) << 16);
    U0.z = (unsigned int)f2bf(ca0[2]) | ((unsigned int)f2bf(cb0[2]) << 16);
    U0.w = (unsigned int)f2bf(ca0[3]) | ((unsigned int)f2bf(cb0[3]) << 16);
    U1.x = (unsigned int)f2bf(ca1[0]) | ((unsigned int)f2bf(cb1[0]) << 16);
    U1.y = (unsigned int)f2bf(ca1[1]) | ((unsigned int)f2bf(cb1[1]) << 16);
    U1.z = (unsigned int)f2bf(ca1[2]) | ((unsigned int)f2bf(cb1[2]) << 16);
    U1.w = (unsigned int)f2bf(ca1[3]) | ((unsigned int)f2bf(cb1[3]) << 16);
    *(uint4*)(dstp + (size_t)(e0 + eb      + m15)*64 + nt4*16 + q*4) = U0;
    *(uint4*)(dstp + (size_t)(e0 + eb + 16 + m15)*64 + nt4*16 + q*4) = U1;
}

__global__ __launch_bounds__(256, 4) void k_mid(
    const int* __restrict__ esrc, const int* __restrict__ edst,
    const float4* __restrict__ eattr4, const float* __restrict__ elen,
    int* __restrict__ cursor, int* __restrict__ esrc_s,
    int* __restrict__ eidx_s, float4* __restrict__ eattrs,
    const unsigned short* __restrict__ w1t,
    const unsigned short* __restrict__ w2t,
    unsigned int* __restrict__ ewAB,
    unsigned int* __restrict__ ewCD,
    const float* __restrict__ ni, const float* __restrict__ attr,
    const float* __restrict__ deg,
    const float* __restrict__ Wli0, const float* __restrict__ Wli1,
    const float* __restrict__ Wlm0, const float* __restrict__ Wlm1,
    ushort4* __restrict__ fvb, float* __restrict__ out)
{
    __shared__ unsigned short Hs[128 * 136];   // mlp: [edge][hid]; node_in: raw f32

    if (blockIdx.x < SCAT_B) {
        // ---------------- scatter branch -----------------------------------
        const int e = blockIdx.x * 256 + threadIdx.x;
        const int p = atomicAdd(&cursor[edst[e]], 1);
        esrc_s[p] = esrc[e];
        eidx_s[p] = e;
        eattrs[p] = eattr4[e];
        return;
    }

    if (blockIdx.x >= SCAT_B + MLP_B) {
        // ---------------- node_in branch (R9-verbatim body) ----------------
        float* raw = reinterpret_cast<float*>(Hs);   // [wave*256 + i]
        const int wave = threadIdx.x >> 6;
        const int lane = threadIdx.x & 63;
        const int n = (blockIdx.x - SCAT_B - MLP_B) * 4 + wave;

        const float* row = ni + (size_t)n * 256;
        raw[wave*256 + lane      ] = row[lane      ];
        raw[wave*256 + lane + 64 ] = row[lane + 64 ];
        raw[wave*256 + lane + 128] = row[lane + 128];
        raw[wave*256 + lane + 192] = row[lane + 192];
        __syncthreads();

        float f0 = 0.f, m0 = 0.f;
        float f1x = 0.f, f1y = 0.f, f1z = 0.f;
        float m1x = 0.f, m1y = 0.f, m1z = 0.f;
        #pragma unroll 4
        for (int t = 0; t < 64; ++t) {
            float xs  = raw[wave*256 + t];
            float xv0 = raw[wave*256 + 64 + t*3    ];
            float xv1 = raw[wave*256 + 64 + t*3 + 1];
            float xv2 = raw[wave*256 + 64 + t*3 + 2];
            float a0 = Wli0[t*64 + lane];
            float a1 = Wli1[t*64 + lane];
            float b0 = Wlm0[t*64 + lane];
            float b1 = Wlm1[t*64 + lane];
            f0  += xs  * a0;   m0  += xs  * b0;
            f1x += xv0 * a1;   f1y += xv1 * a1;   f1z += xv2 * a1;
            m1x += xv0 * b1;   m1y += xv1 * b1;   m1z += xv2 * b1;
        }

        const float a   = attr[n] * INV64;
        const float dis = 1.0f / sqrtf(deg[n]);
        const float fa  = a * dis;

        ushort4 pk;
        pk.x = f2bf(f0  * fa);
        pk.y = f2bf(f1x * fa);
        pk.z = f2bf(f1y * fa);
        pk.w = f2bf(f1z * fa);
        fvb[(size_t)n * 64 + lane] = pk;

        float* orow = out + (size_t)n * 256;
        orow[lane] = C_S * m0 * a;
        orow[64 + lane*3    ] = C_S * m1x * a;
        orow[64 + lane*3 + 1] = C_S * m1y * a;
        orow[64 + lane*3 + 2] = C_S * m1z * a;
        return;
    }

    // ---------------- MLP branch (R9-verbatim pipeline, unsorted edges) ----
    const int t    = threadIdx.x;
    const int w    = t >> 6;
    const int lane = t & 63;
    const int m15  = lane & 15;
    const int q    = lane >> 4;
    const int eb   = w * 32;
    const int e0   = (blockIdx.x - SCAT_B) * 128;

    short8 xa0 = ld_elen8(elen, e0 + eb      + m15, q);
    short8 xa1 = ld_elen8(elen, e0 + eb + 16 + m15, q);

    short8 bw[7];
    #pragma unroll
    for (int nt = 0; nt < 7; ++nt)
        bw[nt] = *(const short8*)(w1t + (nt*16 + m15)*32 + q*8);

    short8 Ba[4], Bb[4], Ca[4], Cb[4];
    p2_ldB(w2t, 0 /*ntA(idx=0)*/, m15, q, Ba, Bb);

    {   // zero hid 112..127 of all 32 rows of this wave
        const int r = eb + (lane >> 1);
        const int c = 112 + (lane & 1) * 8;
        short8 z = {0,0,0,0,0,0,0,0};
        *(short8*)&Hs[r*136 + c] = z;
    }

    // ---- phase 1: D[hid][edge]; lane owns hid nt*16+q*4+{0..3} of edge m15
    #pragma unroll
    for (int nt = 0; nt < 7; ++nt) {
        f32x4 z4 = {0.f, 0.f, 0.f, 0.f};
        f32x4 h0 = __builtin_amdgcn_mfma_f32_16x16x32_bf16(bw[nt], xa0, z4, 0, 0, 0);
        f32x4 h1 = __builtin_amdgcn_mfma_f32_16x16x32_bf16(bw[nt], xa1, z4, 0, 0, 0);
        uint2 d0, d1;
        d0.x = (unsigned int)f2bf(silu_f(h0[0])) | ((unsigned int)f2bf(silu_f(h0[1])) << 16);
        d0.y = (unsigned int)f2bf(silu_f(h0[2])) | ((unsigned int)f2bf(silu_f(h0[3])) << 16);
        d1.x = (unsigned int)f2bf(silu_f(h1[0])) | ((unsigned int)f2bf(silu_f(h1[1])) << 16);
        d1.y = (unsigned int)f2bf(silu_f(h1[2])) | ((unsigned int)f2bf(silu_f(h1[3])) << 16);
        *(uint2*)&Hs[(eb      + m15)*136 + nt*16 + q*4] = d0;
        *(uint2*)&Hs[(eb + 16 + m15)*136 + nt*16 + q*4] = d1;
    }
    // same-wave RAW on Hs -> compiler lgkmcnt, no barrier

    short8 A0[4], A1[4];   // H frags: lane -> (edge m15, k = s*32+q*8+j)
    #pragma unroll
    for (int s = 0; s < 4; ++s) {
        A0[s] = *(const short8*)&Hs[(eb      + m15)*136 + s*32 + q*8];
        A1[s] = *(const short8*)&Hs[(eb + 16 + m15)*136 + s*32 + q*8];
    }

    // ---- phase 2, pipelined: idx = 0..7; grp = idx>>2, nt4 = idx&3,
    // ntA = grp*8 + nt4, dst = grp ? ewCD : ewAB.
    #pragma unroll
    for (int ii = 0; ii < 4; ++ii) {
        const int i0 = 2*ii, i1 = 2*ii + 1;
        const int ntA1 = ((i1 >> 2) * 8) + (i1 & 3);
        p2_ldB(w2t, ntA1, m15, q, Ca, Cb);                     // prefetch odd
        {
            unsigned int* dst0 = (i0 >> 2) ? ewCD : ewAB;
            p2_mfma_store(A0, A1, Ba, Bb, dst0, e0, eb, m15, q, i0 & 3);
        }
        if (ii < 3) {
            const int i2 = i0 + 2;
            const int ntA2 = ((i2 >> 2) * 8) + (i2 & 3);
            p2_ldB(w2t, ntA2, m15, q, Ba, Bb);                 // prefetch next even
        }
        {
            unsigned int* dst1 = (i1 >> 2) ? ewCD : ewAB;
            p2_mfma_store(A0, A1, Ca, Cb, dst1, e0, eb, m15, q, i1 & 3);
        }
    }
}

// ---------------- per-dst gather + fused W_lo GEMM + epilogue ---------------
__global__ __launch_bounds__(256) void k_gather(
    const int* __restrict__ starts, const int* __restrict__ esrc_s,
    const int* __restrict__ eidx_s,
    const float4* __restrict__ eattrs,
    const unsigned int* __restrict__ ewAB,
    const unsigned int* __restrict__ ewCD,
    const ushort4* __restrict__ fvb,
    const float* __restrict__ attr, const float* __restrict__ deg,
    const float* __restrict__ Wlo0, const float* __restrict__ Wlo1,
    float* __restrict__ out)
{
    __shared__ float sm[4][512];
    const int wave = threadIdx.x >> 6;
    const int lane = threadIdx.x & 63;
    const int n = blockIdx.x * 4 + wave;

    const int beg = starts[n], end = starts[n + 1];
    float sA=0.f, sB=0.f;
    float vA0=0.f, vA1=0.f, vA2=0.f;
    float vB0=0.f, vB1=0.f, vB2=0.f;

    for (int base = beg; base < end; base += 64) {
        const int cnt = min(64, end - base);
        int    srcv = 0, eidxv = 0;
        float4 eav  = make_float4(0.f, 0.f, 0.f, 0.f);
        if (lane < cnt) {
            srcv  = esrc_s[base + lane];
            eidxv = eidx_s[base + lane];
            eav   = eattrs[base + lane];
        }
        #pragma unroll 2
        for (int j = 0; j < cnt; ++j) {
            const int   src = __shfl(srcv, j);
            const int   ei  = __shfl(eidxv, j);
            const float y0  = __shfl(eav.x, j);
            const float y10 = __shfl(eav.y, j);
            const float y11 = __shfl(eav.z, j);
            const float y12 = __shfl(eav.w, j);

            const unsigned int uab = ewAB[(size_t)ei*64 + lane];
            const unsigned int ucd = ewCD[(size_t)ei*64 + lane];
            const float wa = bf2f((unsigned short)(uab & 0xFFFFu));
            const float wb = bf2f((unsigned short)(uab >> 16));
            const float wc = bf2f((unsigned short)(ucd & 0xFFFFu));
            const float wd = bf2f((unsigned short)(ucd >> 16));

            const ushort4 g4 = fvb[(size_t)src * 64 + lane];
            const float g0  = bf2f(g4.x);
            const float g10 = bf2f(g4.y);
            const float g11 = bf2f(g4.z);
            const float g12 = bf2f(g4.w);

            const float dotv = g10*y10 + g11*y11 + g12*y12;
            sA += wa * g0 * y0;
            sB += wb * dotv;
            const float t0 = wc * g0;
            vA0 += t0 * y10;  vA1 += t0 * y11;  vA2 += t0 * y12;
            const float t1 = wd * y0;
            vB0 += t1 * g10;  vB1 += t1 * g11;  vB2 += t1 * g12;
        }
    }

    const float dis = 1.0f / sqrtf(deg[n]);
    sm[wave][lane            ] = sA * dis;
    sm[wave][64  + lane      ] = sB * IS3 * dis;
    sm[wave][128 + lane      ] = vA0 * dis;
    sm[wave][128 + 64 + lane ] = vB0 * dis;
    sm[wave][256 + lane      ] = vA1 * dis;
    sm[wave][256 + 64 + lane ] = vB1 * dis;
    sm[wave][384 + lane      ] = vA2 * dis;
    sm[wave][384 + 64 + lane ] = vB2 * dis;
    __syncthreads();

    float o0=0.f, o1x=0.f, o1y=0.f, o1z=0.f;
    #pragma unroll 4
    for (int c = 0; c < 128; ++c) {
        const float w0 = Wlo0[c*64 + lane];
        const float w1 = Wlo1[c*64 + lane];
        o0  += sm[wave][c]         * w0;
        o1x += sm[wave][128 + c]   * w1;
        o1y += sm[wave][256 + c]   * w1;
        o1z += sm[wave][384 + c]   * w1;
    }

    const float a = attr[n] * INVLO;
    float* orow = out + (size_t)n * 256;
    orow[lane] += C_X * o0 * a;
    orow[64 + lane*3    ] += C_X * o1x * a;
    orow[64 + lane*3 + 1] += C_X * o1y * a;
    orow[64 + lane*3 + 2] += C_X * o1z * a;
}

// ======================= fallback (round-1) path ============================
__global__ __launch_bounds__(256) void k_node_in_legacy(
    const float* __restrict__ ni, const float* __restrict__ attr,
    const float* __restrict__ deg,
    const float* __restrict__ Wli0, const float* __restrict__ Wli1,
    const float* __restrict__ Wlm0, const float* __restrict__ Wlm1,
    float* __restrict__ f, float* __restrict__ out)
{
    __shared__ float raw[4][256];
    const int wave = threadIdx.x >> 6;
    const int lane = threadIdx.x & 63;
    const int n = blockIdx.x * 4 + wave;

    const float* row = ni + (size_t)n * 256;
    raw[wave][lane      ] = row[lane      ];
    raw[wave][lane + 64 ] = row[lane + 64 ];
    raw[wave][lane + 128] = row[lane + 128];
    raw[wave][lane + 192] = row[lane + 192];
    __syncthreads();

    float f0 = 0.f, m0 = 0.f;
    float f1x = 0.f, f1y = 0.f, f1z = 0.f;
    float m1x = 0.f, m1y = 0.f, m1z = 0.f;
    for (int t = 0; t < 64; ++t) {
        float xs  = raw[wave][t];
        float xv0 = raw[wave][64 + t*3    ];
        float xv1 = raw[wave][64 + t*3 + 1];
        float xv2 = raw[wave][64 + t*3 + 2];
        float a0 = Wli0[t*64 + lane];
        float a1 = Wli1[t*64 + lane];
        float b0 = Wlm0[t*64 + lane];
        float b1 = Wlm1[t*64 + lane];
        f0  += xs  * a0;   m0  += xs  * b0;
        f1x += xv0 * a1;   f1y += xv1 * a1;   f1z += xv2 * a1;
        m1x += xv0 * b1;   m1y += xv1 * b1;   m1z += xv2 * b1;
    }

    const float a   = attr[n] * INV64;
    const float dis = 1.0f / sqrtf(deg[n]);
    const float fa  = a * dis;

    float* fr = f + (size_t)n * 256;
    fr[lane      ] = f0  * fa;
    fr[64  + lane] = f1x * fa;
    fr[128 + lane] = f1y * fa;
    fr[192 + lane] = f1z * fa;

    float* orow = out + (size_t)n * 256;
    orow[lane] = C_S * m0 * a;
    orow[64 + lane*3    ] = C_S * m1x * a;
    orow[64 + lane*3 + 1] = C_S * m1y * a;
    orow[64 + lane*3 + 2] = C_S * m1z * a;
}

__global__ __launch_bounds__(256) void k_edge_legacy(
    const float* __restrict__ eattr, const float* __restrict__ elen,
    const float* __restrict__ W1, const float* __restrict__ W2,
    const int* __restrict__ esrc, const int* __restrict__ edst,
    const float* __restrict__ f, float* __restrict__ acc)
{
    __shared__ float hsh[4][104];
    const int wave = threadIdx.x >> 6;
    const int lane = threadIdx.x & 63;
    const int e = blockIdx.x * 4 + wave;

    const float* el = elen + (size_t)e * 10;
    float elr[10];
    #pragma unroll
    for (int b = 0; b < 10; ++b) elr[b] = el[b];

    float a1 = 0.f;
    #pragma unroll
    for (int b = 0; b < 10; ++b) a1 += elr[b] * W1[b*100 + lane];
    hsh[wave][lane] = silu_f(a1 * INV1);
    if (lane < 36) {
        float a2 = 0.f;
        #pragma unroll
        for (int b = 0; b < 10; ++b) a2 += elr[b] * W1[b*100 + 64 + lane];
        hsh[wave][64 + lane] = silu_f(a2 * INV1);
    }
    __syncthreads();

    float wa = 0.f, wb = 0.f, wc = 0.f, wd = 0.f;
    for (int j = 0; j < 100; ++j) {
        float hj = hsh[wave][j];
        const float* wr = W2 + j*256;
        wa += hj * wr[lane      ];
        wb += hj * wr[64  + lane];
        wc += hj * wr[128 + lane];
        wd += hj * wr[192 + lane];
    }
    wa *= SC2; wb *= SC2; wc *= SC2; wd *= SC2;

    const int src = esrc[e];
    const int dst = edst[e];
    const float y0  = eattr[e*4 + 0];
    const float y10 = eattr[e*4 + 1];
    const float y11 = eattr[e*4 + 2];
    const float y12 = eattr[e*4 + 3];

    const float* fr = f + (size_t)src * 256;
    const float g0  = fr[lane      ];
    const float g10 = fr[64  + lane];
    const float g11 = fr[128 + lane];
    const float g12 = fr[192 + lane];

    const float dotv = g10*y10 + g11*y11 + g12*y12;

    float* ar = acc + (size_t)dst * 512;
    atomicAdd(ar + lane,                  wa * g0 * y0);
    atomicAdd(ar + 64 + lane,             wb * dotv * IS3);
    atomicAdd(ar + 128 +   0 + lane,      wc * g0 * y10);
    atomicAdd(ar + 128 + 128 + lane,      wc * g0 * y11);
    atomicAdd(ar + 128 + 256 + lane,      wc * g0 * y12);
    atomicAdd(ar + 128 +   0 + 64 + lane, wd * g10 * y0);
    atomicAdd(ar + 128 + 128 + 64 + lane, wd * g11 * y0);
    atomicAdd(ar + 128 + 256 + 64 + lane, wd * g12 * y0);
}

__global__ __launch_bounds__(256) void k_node_out_legacy(
    const float* __restrict__ acc, const float* __restrict__ attr,
    const float* __restrict__ deg, const float* __restrict__ Wlo0,
    const float* __restrict__ Wlo1, float* __restrict__ out)
{
    __shared__ float sm[4][512];
    const int wave = threadIdx.x >> 6;
    const int lane = threadIdx.x & 63;
    const int n = blockIdx.x * 4 + wave;

    const float dis = 1.0f / sqrtf(deg[n]);
    const float* ar = acc + (size_t)n * 512;
    for (int i = lane; i < 512; i += 64) sm[wave][i] = ar[i] * dis;
    __syncthreads();

    float o0 = 0.f, o1x = 0.f, o1y = 0.f, o1z = 0.f;
    for (int c = 0; c < 128; ++c) {
        float w0 = Wlo0[c*64 + lane];
        float w1 = Wlo1[c*64 + lane];
        o0  += sm[wave][c]        * w0;
        o1x += sm[wave][128 + c]  * w1;
        o1y += sm[wave][256 + c]  * w1;
        o1z += sm[wave][384 + c]  * w1;
    }

    const float a = attr[n] * INVLO;
    float* orow = out + (size_t)n * 256;
    orow[lane] += C_X * o0 * a;
    orow[64 + lane*3    ] += C_X * o1x * a;
    orow[64 + lane*3 + 1] += C_X * o1y * a;
    orow[64 + lane*3 + 2] += C_X * o1z * a;
}

// ============================================================================
extern "C" void kernel_launch(void* const* d_in, const int* in_sizes, int n_in,
                              void* d_out, int out_size, void* d_ws, size_t ws_size,
                              hipStream_t stream) {
    const float* ni    = (const float*)d_in[0];
    const float* attr  = (const float*)d_in[1];
    const float* deg   = (const float*)d_in[2];
    const float* eattr = (const float*)d_in[3];
    const float* elen  = (const float*)d_in[4];
    const float* Wli0  = (const float*)d_in[5];
    const float* Wli1  = (const float*)d_in[6];
    const float* Wlm0  = (const float*)d_in[7];
    const float* Wlm1  = (const float*)d_in[8];
    const float* Wm1   = (const float*)d_in[9];
    const float* Wm2   = (const float*)d_in[10];
    const float* Wlo0  = (const float*)d_in[11];
    const float* Wlo1  = (const float*)d_in[12];
    const int*   esrc  = (const int*)d_in[13];
    const int*   edst  = (const int*)d_in[14];

    float* out = (float*)d_out;

    // ws layout (fast path), 16 B-aligned sections
    char* wsb = (char*)d_ws;
    size_t off = 0;
    ushort4* fvb = (ushort4*)(wsb + off);               off += (size_t)N_NODES * 64 * 8;    // 10.24 MB
    unsigned int* ewAB = (unsigned int*)(wsb + off);    off += (size_t)N_EDGES * 64 * 4;    // 81.92 MB
    unsigned int* ewCD = (unsigned int*)(wsb + off);    off += (size_t)N_EDGES * 64 * 4;    // 81.92 MB
    float4* eattrs = (float4*)(wsb + off);              off += (size_t)N_EDGES * 16;        // 5.12 MB
    int* esrc_s = (int*)(wsb + off);                    off += (size_t)N_EDGES * 4;         // 1.28 MB
    int* eidx_s = (int*)(wsb + off);                    off += (size_t)N_EDGES * 4;         // 1.28 MB
    unsigned short* w2t = (unsigned short*)(wsb + off); off += 32768 * 2;
    unsigned short* w1t = (unsigned short*)(wsb + off); off += 3584 * 2;
    int* starts = (int*)(wsb + off);                    off += (size_t)(N_NODES + 4) * 4;
    int* hist   = (int*)(wsb + off);                    off += (size_t)N_NODES * 4;
    int* cursor = (int*)(wsb + off);                    off += (size_t)N_NODES * 4;
    const size_t need_fast = off;

    if (ws_size >= need_fast) {
        hipMemsetAsync(hist, 0, (size_t)N_NODES * sizeof(int), stream);
        k_prep2  <<<N_EDGES / 256 + 144, 256, 0, stream>>>(edst, hist,
                                                           Wm2, Wm1, w2t, w1t);
        k_scan   <<<1, 1024, 0, stream>>>(hist, starts, cursor);
        k_mid    <<<SCAT_B + MLP_B + NODE_B, 256, 0, stream>>>(
                     esrc, edst, (const float4*)eattr, elen,
                     cursor, esrc_s, eidx_s, eattrs,
                     w1t, w2t, ewAB, ewCD,
                     ni, attr, deg, Wli0, Wli1, Wlm0, Wlm1, fvb, out);
        k_gather <<<N_NODES / 4, 256, 0, stream>>>(starts, esrc_s, eidx_s,
                                                   eattrs, ewAB, ewCD,
                                                   fvb, attr, deg,
                                                   Wlo0, Wlo1, out);
    } else {
        // fallback: round-1 atomic path (61.4 MB scratch)
        float* f   = (float*)d_ws;
        float* acc = f + (size_t)N_NODES * 256;
        hipMemsetAsync(acc, 0, (size_t)N_NODES * 512 * sizeof(float), stream);
        k_node_in_legacy<<<N_NODES / 4, 256, 0, stream>>>(ni, attr, deg, Wli0, Wli1,
                                                          Wlm0, Wlm1, f, out);
        k_edge_legacy<<<N_EDGES / 4, 256, 0, stream>>>(eattr, elen, Wm1, Wm2,
                                                       esrc, edst, f, acc);
        k_node_out_legacy<<<N_NODES / 4, 256, 0, stream>>>(acc, attr, deg,
                                                           Wlo0, Wlo1, out);
    }
}

// Round 13
// 389.612 us; speedup vs baseline: 1.0015x; 1.0015x over previous
//
#include <hip/hip_runtime.h>
#include <hip/hip_bf16.h>
#include <math.h>

#define N_NODES 20000
#define N_EDGES 320000

#define INV1   0.31622776601683794f   // 1/sqrt(10)
#define SC2    0.1f                   // 1/sqrt(100)
#define IS3    0.5773502691896258f    // 1/sqrt(3)
#define C_S    0.3826834323650898f    // sin(pi/8)
#define C_X    0.9238795325112867f    // cos(pi/8)
#define INV64  0.125f                 // 1/sqrt(64)
#define INVLO  0.08838834764831845f   // 1/sqrt(128)

typedef short     short8 __attribute__((ext_vector_type(8)));
typedef float     f32x4  __attribute__((ext_vector_type(4)));

// fast silu: x * rcp(1 + exp2(-x*log2(e))) — verified passing (round 3).
__device__ __forceinline__ float silu_f(float x) {
    float e = __builtin_amdgcn_exp2f(-1.44269504088896f * x);
    return x * __builtin_amdgcn_rcpf(1.0f + e);
}
// software RNE f32->bf16 (verified). NOTE: v_cvt_pk_bf16_f32 inline asm
// produced NaN garbage on this toolchain (round 1/2) — do not reintroduce.
// NOTE (round 10): fp8-e4m3 ew interface fails absmax (0.094 > 0.085) —
// interface must stay bf16.
__device__ __forceinline__ unsigned short f2bf(float x) {
    __hip_bfloat16 h = __float2bfloat16(x);
    return *reinterpret_cast<unsigned short*>(&h);
}
__device__ __forceinline__ float bf2f(unsigned short u) {
    __hip_bfloat16 h;
    *reinterpret_cast<unsigned short*>(&h) = u;
    return __bfloat162float(h);
}

// ---------------- merged pre-pass (R11 best config) -------------------------
// blocks [0, 5000): node_in  (fvb + out = c_s*m)
// blocks [5000, 6250): edge-dst histogram
// blocks [6250, 6394): W2/W1 bf16 transpose prep
__global__ __launch_bounds__(256) void k_pre(
    const float* __restrict__ ni, const float* __restrict__ attr,
    const float* __restrict__ deg,
    const float* __restrict__ Wli0, const float* __restrict__ Wli1,
    const float* __restrict__ Wlm0, const float* __restrict__ Wlm1,
    ushort4* __restrict__ fvb, float* __restrict__ out,
    const int* __restrict__ edst, int* __restrict__ hist,
    const float* __restrict__ W2, const float* __restrict__ W1,
    unsigned short* __restrict__ w2t, unsigned short* __restrict__ w1t)
{
    __shared__ float raw[4][256];
    if (blockIdx.x < N_NODES / 4) {
        const int wave = threadIdx.x >> 6;
        const int lane = threadIdx.x & 63;
        const int n = blockIdx.x * 4 + wave;

        const float* row = ni + (size_t)n * 256;
        raw[wave][lane      ] = row[lane      ];
        raw[wave][lane + 64 ] = row[lane + 64 ];
        raw[wave][lane + 128] = row[lane + 128];
        raw[wave][lane + 192] = row[lane + 192];
        __syncthreads();

        float f0 = 0.f, m0 = 0.f;
        float f1x = 0.f, f1y = 0.f, f1z = 0.f;
        float m1x = 0.f, m1y = 0.f, m1z = 0.f;
        #pragma unroll 4
        for (int t = 0; t < 64; ++t) {
            float xs  = raw[wave][t];
            float xv0 = raw[wave][64 + t*3    ];
            float xv1 = raw[wave][64 + t*3 + 1];
            float xv2 = raw[wave][64 + t*3 + 2];
            float a0 = Wli0[t*64 + lane];
            float a1 = Wli1[t*64 + lane];
            float b0 = Wlm0[t*64 + lane];
            float b1 = Wlm1[t*64 + lane];
            f0  += xs  * a0;   m0  += xs  * b0;
            f1x += xv0 * a1;   f1y += xv1 * a1;   f1z += xv2 * a1;
            m1x += xv0 * b1;   m1y += xv1 * b1;   m1z += xv2 * b1;
        }

        const float a   = attr[n] * INV64;
        const float dis = 1.0f / sqrtf(deg[n]);
        const float fa  = a * dis;

        ushort4 pk;
        pk.x = f2bf(f0  * fa);
        pk.y = f2bf(f1x * fa);
        pk.z = f2bf(f1y * fa);
        pk.w = f2bf(f1z * fa);
        fvb[(size_t)n * 64 + lane] = pk;

        float* orow = out + (size_t)n * 256;
        orow[lane] = C_S * m0 * a;
        orow[64 + lane*3    ] = C_S * m1x * a;
        orow[64 + lane*3 + 1] = C_S * m1y * a;
        orow[64 + lane*3 + 2] = C_S * m1z * a;
    } else if (blockIdx.x < N_NODES / 4 + N_EDGES / 256) {
        const int e = (blockIdx.x - N_NODES / 4) * 256 + threadIdx.x;
        atomicAdd(&hist[edst[e]], 1);
    } else {
        const int i = (blockIdx.x - N_NODES / 4 - N_EDGES / 256) * 256
                    + threadIdx.x;
        if (i < 32768) {
            const int n = i >> 7, k = i & 127;
            w2t[i] = (k < 100) ? f2bf(W2[k*256 + n] * SC2) : (unsigned short)0;
        } else if (i < 32768 + 3584) {
            const int j = i - 32768;
            const int n = j >> 5, k = j & 31;
            w1t[j] = (k < 10 && n < 100) ? f2bf(W1[k*100 + n] * INV1)
                                         : (unsigned short)0;
        }
    }
}

__global__ __launch_bounds__(1024) void k_scan(const int* __restrict__ hist,
                                               int* __restrict__ starts,
                                               int* __restrict__ cursor) {
    __shared__ int part[1024];
    const int t = threadIdx.x;
    const int C = 20;
    const int base = t * C;
    int s = 0;
    for (int i = 0; i < C; ++i) {
        const int idx = base + i;
        if (idx < N_NODES) s += hist[idx];
    }
    part[t] = s;
    __syncthreads();
    for (int off = 1; off < 1024; off <<= 1) {
        int v = (t >= off) ? part[t - off] : 0;
        __syncthreads();
        part[t] += v;
        __syncthreads();
    }
    int run = part[t] - s;
    for (int i = 0; i < C; ++i) {
        const int idx = base + i;
        if (idx < N_NODES) {
            starts[idx] = run;
            cursor[idx] = run;
            run += hist[idx];
        }
    }
    if (t == 1023) starts[N_NODES] = N_EDGES;
}

// ---------------- merged mid-pass: scatter (sort) || edge-MLP (unsorted) ----
// R11-verbatim: ew computed in ORIGINAL edge order (depends only on elen);
//   blocks [0, 1250):    scatter — sort esrc/eattr/eidx by dst
//   blocks [1250, 3750): MLP     — MFMA pipeline, elen read f32
// k_gather indexes ew rows via eidx_s (row reads stay 64-lane coalesced).

// load one edge's elen slice as bf16 short8: lane-q covers elems q*8..q*8+7;
// row is 10 floats, so q=1 has elems 8,9 valid + 6 zeros.
__device__ __forceinline__ short8 ld_elen8(const float* __restrict__ elen,
                                           int e, int q)
{
    const float* er = elen + (size_t)e * 10 + q * 8;
    float v0 = er[0], v1 = er[1];
    float v2 = 0.f, v3 = 0.f, v4 = 0.f, v5 = 0.f, v6 = 0.f, v7 = 0.f;
    if (q == 0) {
        v2 = er[2]; v3 = er[3]; v4 = er[4];
        v5 = er[5]; v6 = er[6]; v7 = er[7];
    }
    short8 r;
    r[0] = (short)f2bf(v0); r[1] = (short)f2bf(v1);
    r[2] = (short)f2bf(v2); r[3] = (short)f2bf(v3);
    r[4] = (short)f2bf(v4); r[5] = (short)f2bf(v5);
    r[6] = (short)f2bf(v6); r[7] = (short)f2bf(v7);
    return r;
}

__device__ __forceinline__ void p2_ldB(const unsigned short* __restrict__ w2t,
                                       int ntA, int m15, int q,
                                       short8* BA, short8* BB)
{
    const unsigned short* bpA = w2t + ((size_t)(ntA*16 + m15) << 7);
    const unsigned short* bpB = w2t + ((size_t)((ntA + 4)*16 + m15) << 7);
    #pragma unroll
    for (int s = 0; s < 4; ++s) {
        BA[s] = *(const short8*)(bpA + s*32 + q*8);
        BB[s] = *(const short8*)(bpB + s*32 + q*8);
    }
}

__device__ __forceinline__ void p2_mfma_store(
    const short8* A0, const short8* A1,
    const short8* BA, const short8* BB,
    unsigned int* __restrict__ dstp,
    int e0, int eb, int m15, int q, int nt4)
{
    f32x4 ca0 = {0.f,0.f,0.f,0.f}, ca1 = {0.f,0.f,0.f,0.f};
    f32x4 cb0 = {0.f,0.f,0.f,0.f}, cb1 = {0.f,0.f,0.f,0.f};
    #pragma unroll
    for (int s = 0; s < 4; ++s) {
        ca0 = __builtin_amdgcn_mfma_f32_16x16x32_bf16(BA[s], A0[s], ca0, 0, 0, 0);
        ca1 = __builtin_amdgcn_mfma_f32_16x16x32_bf16(BA[s], A1[s], ca1, 0, 0, 0);
        cb0 = __builtin_amdgcn_mfma_f32_16x16x32_bf16(BB[s], A0[s], cb0, 0, 0, 0);
        cb1 = __builtin_amdgcn_mfma_f32_16x16x32_bf16(BB[s], A1[s], cb1, 0, 0, 0);
    }
    uint4 U0, U1;
    U0.x = (unsigned int)f2bf(ca0[0]) | ((unsigned int)f2bf(cb0[0]) << 16);
    U0.y = (unsigned int)f2bf(ca0[1]) | ((unsigned int)f2bf(cb0[1]) << 16);
    U0.z = (unsigned int)f2bf(ca0[2]) | ((unsigned int)f2bf(cb0[2]) << 16);
    U0.w = (unsigned int)f2bf(ca0[3]) | ((unsigned int)f2bf(cb0[3]) << 16);
    U1.x = (unsigned int)f2bf(ca1[0]) | ((unsigned int)f2bf(cb1[0]) << 16);
    U1.y = (unsigned int)f2bf(ca1[1]) | ((unsigned int)f2bf(cb1[1]) << 16);
    U1.z = (unsigned int)f2bf(ca1[2]) | ((unsigned int)f2bf(cb1[2]) << 16);
    U1.w = (unsigned int)f2bf(ca1[3]) | ((unsigned int)f2bf(cb1[3]) << 16);
    *(uint4*)(dstp + (size_t)(e0 + eb      + m15)*64 + nt4*16 + q*4) = U0;
    *(uint4*)(dstp + (size_t)(e0 + eb + 16 + m15)*64 + nt4*16 + q*4) = U1;
}

__global__ __launch_bounds__(256, 4) void k_mid(
    const int* __restrict__ esrc, const int* __restrict__ edst,
    const float4* __restrict__ eattr4, const float* __restrict__ elen,
    int* __restrict__ cursor, int* __restrict__ esrc_s,
    int* __restrict__ eidx_s, float4* __restrict__ eattrs,
    const unsigned short* __restrict__ w1t,
    const unsigned short* __restrict__ w2t,
    unsigned int* __restrict__ ewAB,
    unsigned int* __restrict__ ewCD)
{
    __shared__ unsigned short Hs[128 * 136];   // [edge][hid] stride 136

    if (blockIdx.x < N_EDGES / 256) {
        // ---------------- scatter branch -----------------------------------
        const int e = blockIdx.x * 256 + threadIdx.x;
        const int p = atomicAdd(&cursor[edst[e]], 1);
        esrc_s[p] = esrc[e];
        eidx_s[p] = e;
        eattrs[p] = eattr4[e];
        return;
    }

    // ---------------- MLP branch (unsorted edges) --------------------------
    const int t    = threadIdx.x;
    const int w    = t >> 6;
    const int lane = t & 63;
    const int m15  = lane & 15;
    const int q    = lane >> 4;
    const int eb   = w * 32;
    const int e0   = (blockIdx.x - N_EDGES / 256) * 128;

    short8 xa0 = ld_elen8(elen, e0 + eb      + m15, q);
    short8 xa1 = ld_elen8(elen, e0 + eb + 16 + m15, q);

    short8 bw[7];
    #pragma unroll
    for (int nt = 0; nt < 7; ++nt)
        bw[nt] = *(const short8*)(w1t + (nt*16 + m15)*32 + q*8);

    short8 Ba[4], Bb[4], Ca[4], Cb[4];
    p2_ldB(w2t, 0 /*ntA(idx=0)*/, m15, q, Ba, Bb);

    {   // zero hid 112..127 of all 32 rows of this wave
        const int r = eb + (lane >> 1);
        const int c = 112 + (lane & 1) * 8;
        short8 z = {0,0,0,0,0,0,0,0};
        *(short8*)&Hs[r*136 + c] = z;
    }

    // ---- phase 1: D[hid][edge]; lane owns hid nt*16+q*4+{0..3} of edge m15
    #pragma unroll
    for (int nt = 0; nt < 7; ++nt) {
        f32x4 z4 = {0.f, 0.f, 0.f, 0.f};
        f32x4 h0 = __builtin_amdgcn_mfma_f32_16x16x32_bf16(bw[nt], xa0, z4, 0, 0, 0);
        f32x4 h1 = __builtin_amdgcn_mfma_f32_16x16x32_bf16(bw[nt], xa1, z4, 0, 0, 0);
        uint2 d0, d1;
        d0.x = (unsigned int)f2bf(silu_f(h0[0])) | ((unsigned int)f2bf(silu_f(h0[1])) << 16);
        d0.y = (unsigned int)f2bf(silu_f(h0[2])) | ((unsigned int)f2bf(silu_f(h0[3])) << 16);
        d1.x = (unsigned int)f2bf(silu_f(h1[0])) | ((unsigned int)f2bf(silu_f(h1[1])) << 16);
        d1.y = (unsigned int)f2bf(silu_f(h1[2])) | ((unsigned int)f2bf(silu_f(h1[3])) << 16);
        *(uint2*)&Hs[(eb      + m15)*136 + nt*16 + q*4] = d0;
        *(uint2*)&Hs[(eb + 16 + m15)*136 + nt*16 + q*4] = d1;
    }
    // same-wave RAW on Hs -> compiler lgkmcnt, no barrier

    short8 A0[4], A1[4];   // H frags: lane -> (edge m15, k = s*32+q*8+j)
    #pragma unroll
    for (int s = 0; s < 4; ++s) {
        A0[s] = *(const short8*)&Hs[(eb      + m15)*136 + s*32 + q*8];
        A1[s] = *(const short8*)&Hs[(eb + 16 + m15)*136 + s*32 + q*8];
    }

    // ---- phase 2, pipelined: idx = 0..7; grp = idx>>2, nt4 = idx&3,
    // ntA = grp*8 + nt4, dst = grp ? ewCD : ewAB.
    #pragma unroll
    for (int ii = 0; ii < 4; ++ii) {
        const int i0 = 2*ii, i1 = 2*ii + 1;
        const int ntA1 = ((i1 >> 2) * 8) + (i1 & 3);
        p2_ldB(w2t, ntA1, m15, q, Ca, Cb);                     // prefetch odd
        {
            unsigned int* dst0 = (i0 >> 2) ? ewCD : ewAB;
            p2_mfma_store(A0, A1, Ba, Bb, dst0, e0, eb, m15, q, i0 & 3);
        }
        if (ii < 3) {
            const int i2 = i0 + 2;
            const int ntA2 = ((i2 >> 2) * 8) + (i2 & 3);
            p2_ldB(w2t, ntA2, m15, q, Ba, Bb);                 // prefetch next even
        }
        {
            unsigned int* dst1 = (i1 >> 2) ? ewCD : ewAB;
            p2_mfma_store(A0, A1, Ca, Cb, dst1, e0, eb, m15, q, i1 & 3);
        }
    }
}

// ---------------- per-dst gather + fused W_lo GEMM + epilogue ---------------
// Round-13: single change vs R11 — j-loop unroll 2 -> 4 (deeper MLP on the
// three independent loads per iteration: ewAB, ewCD, fvb row).
__global__ __launch_bounds__(256) void k_gather(
    const int* __restrict__ starts, const int* __restrict__ esrc_s,
    const int* __restrict__ eidx_s,
    const float4* __restrict__ eattrs,
    const unsigned int* __restrict__ ewAB,
    const unsigned int* __restrict__ ewCD,
    const ushort4* __restrict__ fvb,
    const float* __restrict__ attr, const float* __restrict__ deg,
    const float* __restrict__ Wlo0, const float* __restrict__ Wlo1,
    float* __restrict__ out)
{
    __shared__ float sm[4][512];
    const int wave = threadIdx.x >> 6;
    const int lane = threadIdx.x & 63;
    const int n = blockIdx.x * 4 + wave;

    const int beg = starts[n], end = starts[n + 1];
    float sA=0.f, sB=0.f;
    float vA0=0.f, vA1=0.f, vA2=0.f;
    float vB0=0.f, vB1=0.f, vB2=0.f;

    for (int base = beg; base < end; base += 64) {
        const int cnt = min(64, end - base);
        int    srcv = 0, eidxv = 0;
        float4 eav  = make_float4(0.f, 0.f, 0.f, 0.f);
        if (lane < cnt) {
            srcv  = esrc_s[base + lane];
            eidxv = eidx_s[base + lane];
            eav   = eattrs[base + lane];
        }
        #pragma unroll 4
        for (int j = 0; j < cnt; ++j) {
            const int   src = __shfl(srcv, j);
            const int   ei  = __shfl(eidxv, j);
            const float y0  = __shfl(eav.x, j);
            const float y10 = __shfl(eav.y, j);
            const float y11 = __shfl(eav.z, j);
            const float y12 = __shfl(eav.w, j);

            const unsigned int uab = ewAB[(size_t)ei*64 + lane];
            const unsigned int ucd = ewCD[(size_t)ei*64 + lane];
            const float wa = bf2f((unsigned short)(uab & 0xFFFFu));
            const float wb = bf2f((unsigned short)(uab >> 16));
            const float wc = bf2f((unsigned short)(ucd & 0xFFFFu));
            const float wd = bf2f((unsigned short)(ucd >> 16));

            const ushort4 g4 = fvb[(size_t)src * 64 + lane];
            const float g0  = bf2f(g4.x);
            const float g10 = bf2f(g4.y);
            const float g11 = bf2f(g4.z);
            const float g12 = bf2f(g4.w);

            const float dotv = g10*y10 + g11*y11 + g12*y12;
            sA += wa * g0 * y0;
            sB += wb * dotv;
            const float t0 = wc * g0;
            vA0 += t0 * y10;  vA1 += t0 * y11;  vA2 += t0 * y12;
            const float t1 = wd * y0;
            vB0 += t1 * g10;  vB1 += t1 * g11;  vB2 += t1 * g12;
        }
    }

    const float dis = 1.0f / sqrtf(deg[n]);
    sm[wave][lane            ] = sA * dis;
    sm[wave][64  + lane      ] = sB * IS3 * dis;
    sm[wave][128 + lane      ] = vA0 * dis;
    sm[wave][128 + 64 + lane ] = vB0 * dis;
    sm[wave][256 + lane      ] = vA1 * dis;
    sm[wave][256 + 64 + lane ] = vB1 * dis;
    sm[wave][384 + lane      ] = vA2 * dis;
    sm[wave][384 + 64 + lane ] = vB2 * dis;
    __syncthreads();

    float o0=0.f, o1x=0.f, o1y=0.f, o1z=0.f;
    #pragma unroll 4
    for (int c = 0; c < 128; ++c) {
        const float w0 = Wlo0[c*64 + lane];
        const float w1 = Wlo1[c*64 + lane];
        o0  += sm[wave][c]         * w0;
        o1x += sm[wave][128 + c]   * w1;
        o1y += sm[wave][256 + c]   * w1;
        o1z += sm[wave][384 + c]   * w1;
    }

    const float a = attr[n] * INVLO;
    float* orow = out + (size_t)n * 256;
    orow[lane] += C_X * o0 * a;
    orow[64 + lane*3    ] += C_X * o1x * a;
    orow[64 + lane*3 + 1] += C_X * o1y * a;
    orow[64 + lane*3 + 2] += C_X * o1z * a;
}

// ======================= fallback (round-1) path ============================
__global__ __launch_bounds__(256) void k_node_in_legacy(
    const float* __restrict__ ni, const float* __restrict__ attr,
    const float* __restrict__ deg,
    const float* __restrict__ Wli0, const float* __restrict__ Wli1,
    const float* __restrict__ Wlm0, const float* __restrict__ Wlm1,
    float* __restrict__ f, float* __restrict__ out)
{
    __shared__ float raw[4][256];
    const int wave = threadIdx.x >> 6;
    const int lane = threadIdx.x & 63;
    const int n = blockIdx.x * 4 + wave;

    const float* row = ni + (size_t)n * 256;
    raw[wave][lane      ] = row[lane      ];
    raw[wave][lane + 64 ] = row[lane + 64 ];
    raw[wave][lane + 128] = row[lane + 128];
    raw[wave][lane + 192] = row[lane + 192];
    __syncthreads();

    float f0 = 0.f, m0 = 0.f;
    float f1x = 0.f, f1y = 0.f, f1z = 0.f;
    float m1x = 0.f, m1y = 0.f, m1z = 0.f;
    for (int t = 0; t < 64; ++t) {
        float xs  = raw[wave][t];
        float xv0 = raw[wave][64 + t*3    ];
        float xv1 = raw[wave][64 + t*3 + 1];
        float xv2 = raw[wave][64 + t*3 + 2];
        float a0 = Wli0[t*64 + lane];
        float a1 = Wli1[t*64 + lane];
        float b0 = Wlm0[t*64 + lane];
        float b1 = Wlm1[t*64 + lane];
        f0  += xs  * a0;   m0  += xs  * b0;
        f1x += xv0 * a1;   f1y += xv1 * a1;   f1z += xv2 * a1;
        m1x += xv0 * b1;   m1y += xv1 * b1;   m1z += xv2 * b1;
    }

    const float a   = attr[n] * INV64;
    const float dis = 1.0f / sqrtf(deg[n]);
    const float fa  = a * dis;

    float* fr = f + (size_t)n * 256;
    fr[lane      ] = f0  * fa;
    fr[64  + lane] = f1x * fa;
    fr[128 + lane] = f1y * fa;
    fr[192 + lane] = f1z * fa;

    float* orow = out + (size_t)n * 256;
    orow[lane] = C_S * m0 * a;
    orow[64 + lane*3    ] = C_S * m1x * a;
    orow[64 + lane*3 + 1] = C_S * m1y * a;
    orow[64 + lane*3 + 2] = C_S * m1z * a;
}

__global__ __launch_bounds__(256) void k_edge_legacy(
    const float* __restrict__ eattr, const float* __restrict__ elen,
    const float* __restrict__ W1, const float* __restrict__ W2,
    const int* __restrict__ esrc, const int* __restrict__ edst,
    const float* __restrict__ f, float* __restrict__ acc)
{
    __shared__ float hsh[4][104];
    const int wave = threadIdx.x >> 6;
    const int lane = threadIdx.x & 63;
    const int e = blockIdx.x * 4 + wave;

    const float* el = elen + (size_t)e * 10;
    float elr[10];
    #pragma unroll
    for (int b = 0; b < 10; ++b) elr[b] = el[b];

    float a1 = 0.f;
    #pragma unroll
    for (int b = 0; b < 10; ++b) a1 += elr[b] * W1[b*100 + lane];
    hsh[wave][lane] = silu_f(a1 * INV1);
    if (lane < 36) {
        float a2 = 0.f;
        #pragma unroll
        for (int b = 0; b < 10; ++b) a2 += elr[b] * W1[b*100 + 64 + lane];
        hsh[wave][64 + lane] = silu_f(a2 * INV1);
    }
    __syncthreads();

    float wa = 0.f, wb = 0.f, wc = 0.f, wd = 0.f;
    for (int j = 0; j < 100; ++j) {
        float hj = hsh[wave][j];
        const float* wr = W2 + j*256;
        wa += hj * wr[lane      ];
        wb += hj * wr[64  + lane];
        wc += hj * wr[128 + lane];
        wd += hj * wr[192 + lane];
    }
    wa *= SC2; wb *= SC2; wc *= SC2; wd *= SC2;

    const int src = esrc[e];
    const int dst = edst[e];
    const float y0  = eattr[e*4 + 0];
    const float y10 = eattr[e*4 + 1];
    const float y11 = eattr[e*4 + 2];
    const float y12 = eattr[e*4 + 3];

    const float* fr = f + (size_t)src * 256;
    const float g0  = fr[lane      ];
    const float g10 = fr[64  + lane];
    const float g11 = fr[128 + lane];
    const float g12 = fr[192 + lane];

    const float dotv = g10*y10 + g11*y11 + g12*y12;

    float* ar = acc + (size_t)dst * 512;
    atomicAdd(ar + lane,                  wa * g0 * y0);
    atomicAdd(ar + 64 + lane,             wb * dotv * IS3);
    atomicAdd(ar + 128 +   0 + lane,      wc * g0 * y10);
    atomicAdd(ar + 128 + 128 + lane,      wc * g0 * y11);
    atomicAdd(ar + 128 + 256 + lane,      wc * g0 * y12);
    atomicAdd(ar + 128 +   0 + 64 + lane, wd * g10 * y0);
    atomicAdd(ar + 128 + 128 + 64 + lane, wd * g11 * y0);
    atomicAdd(ar + 128 + 256 + 64 + lane, wd * g12 * y0);
}

__global__ __launch_bounds__(256) void k_node_out_legacy(
    const float* __restrict__ acc, const float* __restrict__ attr,
    const float* __restrict__ deg, const float* __restrict__ Wlo0,
    const float* __restrict__ Wlo1, float* __restrict__ out)
{
    __shared__ float sm[4][512];
    const int wave = threadIdx.x >> 6;
    const int lane = threadIdx.x & 63;
    const int n = blockIdx.x * 4 + wave;

    const float dis = 1.0f / sqrtf(deg[n]);
    const float* ar = acc + (size_t)n * 512;
    for (int i = lane; i < 512; i += 64) sm[wave][i] = ar[i] * dis;
    __syncthreads();

    float o0 = 0.f, o1x = 0.f, o1y = 0.f, o1z = 0.f;
    for (int c = 0; c < 128; ++c) {
        float w0 = Wlo0[c*64 + lane];
        float w1 = Wlo1[c*64 + lane];
        o0  += sm[wave][c]        * w0;
        o1x += sm[wave][128 + c]  * w1;
        o1y += sm[wave][256 + c]  * w1;
        o1z += sm[wave][384 + c]  * w1;
    }

    const float a = attr[n] * INVLO;
    float* orow = out + (size_t)n * 256;
    orow[lane] += C_X * o0 * a;
    orow[64 + lane*3    ] += C_X * o1x * a;
    orow[64 + lane*3 + 1] += C_X * o1y * a;
    orow[64 + lane*3 + 2] += C_X * o1z * a;
}

// ============================================================================
extern "C" void kernel_launch(void* const* d_in, const int* in_sizes, int n_in,
                              void* d_out, int out_size, void* d_ws, size_t ws_size,
                              hipStream_t stream) {
    const float* ni    = (const float*)d_in[0];
    const float* attr  = (const float*)d_in[1];
    const float* deg   = (const float*)d_in[2];
    const float* eattr = (const float*)d_in[3];
    const float* elen  = (const float*)d_in[4];
    const float* Wli0  = (const float*)d_in[5];
    const float* Wli1  = (const float*)d_in[6];
    const float* Wlm0  = (const float*)d_in[7];
    const float* Wlm1  = (const float*)d_in[8];
    const float* Wm1   = (const float*)d_in[9];
    const float* Wm2   = (const float*)d_in[10];
    const float* Wlo0  = (const float*)d_in[11];
    const float* Wlo1  = (const float*)d_in[12];
    const int*   esrc  = (const int*)d_in[13];
    const int*   edst  = (const int*)d_in[14];

    float* out = (float*)d_out;

    // ws layout (fast path), 16 B-aligned sections
    char* wsb = (char*)d_ws;
    size_t off = 0;
    ushort4* fvb = (ushort4*)(wsb + off);               off += (size_t)N_NODES * 64 * 8;    // 10.24 MB
    unsigned int* ewAB = (unsigned int*)(wsb + off);    off += (size_t)N_EDGES * 64 * 4;    // 81.92 MB
    unsigned int* ewCD = (unsigned int*)(wsb + off);    off += (size_t)N_EDGES * 64 * 4;    // 81.92 MB
    float4* eattrs = (float4*)(wsb + off);              off += (size_t)N_EDGES * 16;        // 5.12 MB
    int* esrc_s = (int*)(wsb + off);                    off += (size_t)N_EDGES * 4;         // 1.28 MB
    int* eidx_s = (int*)(wsb + off);                    off += (size_t)N_EDGES * 4;         // 1.28 MB
    unsigned short* w2t = (unsigned short*)(wsb + off); off += 32768 * 2;
    unsigned short* w1t = (unsigned short*)(wsb + off); off += 3584 * 2;
    int* starts = (int*)(wsb + off);                    off += (size_t)(N_NODES + 4) * 4;
    int* hist   = (int*)(wsb + off);                    off += (size_t)N_NODES * 4;
    int* cursor = (int*)(wsb + off);                    off += (size_t)N_NODES * 4;
    const size_t need_fast = off;

    if (ws_size >= need_fast) {
        hipMemsetAsync(hist, 0, (size_t)N_NODES * sizeof(int), stream);
        k_pre    <<<N_NODES / 4 + N_EDGES / 256 + 144, 256, 0, stream>>>(
                     ni, attr, deg, Wli0, Wli1, Wlm0, Wlm1, fvb, out,
                     edst, hist, Wm2, Wm1, w2t, w1t);
        k_scan   <<<1, 1024, 0, stream>>>(hist, starts, cursor);
        k_mid    <<<N_EDGES / 256 + N_EDGES / 128, 256, 0, stream>>>(
                     esrc, edst, (const float4*)eattr, elen,
                     cursor, esrc_s, eidx_s, eattrs,
                     w1t, w2t, ewAB, ewCD);
        k_gather <<<N_NODES / 4, 256, 0, stream>>>(starts, esrc_s, eidx_s,
                                                   eattrs, ewAB, ewCD,
                                                   fvb, attr, deg,
                                                   Wlo0, Wlo1, out);
    } else {
        // fallback: round-1 atomic path (61.4 MB scratch)
        float* f   = (float*)d_ws;
        float* acc = f + (size_t)N_NODES * 256;
        hipMemsetAsync(acc, 0, (size_t)N_NODES * 512 * sizeof(float), stream);
        k_node_in_legacy<<<N_NODES / 4, 256, 0, stream>>>(ni, attr, deg, Wli0, Wli1,
                                                          Wlm0, Wlm1, f, out);
        k_edge_legacy<<<N_EDGES / 4, 256, 0, stream>>>(eattr, elen, Wm1, Wm2,
                                                       esrc, edst, f, acc);
        k_node_out_legacy<<<N_NODES / 4, 256, 0, stream>>>(acc, attr, deg,
                                                           Wlo0, Wlo1, out);
    }
}

// Round 14
// 373.060 us; speedup vs baseline: 1.0459x; 1.0444x over previous
//
#include <hip/hip_runtime.h>
#include <hip/hip_bf16.h>
#include <math.h>

#define N_NODES 20000
#define N_EDGES 320000

#define INV1   0.31622776601683794f   // 1/sqrt(10)
#define SC2    0.1f                   // 1/sqrt(100)
#define IS3    0.5773502691896258f    // 1/sqrt(3)
#define C_S    0.3826834323650898f    // sin(pi/8)
#define C_X    0.9238795325112867f    // cos(pi/8)
#define INV64  0.125f                 // 1/sqrt(64)
#define INVLO  0.08838834764831845f   // 1/sqrt(128)

typedef short     short8 __attribute__((ext_vector_type(8)));
typedef float     f32x4  __attribute__((ext_vector_type(4)));

// fast silu: x * rcp(1 + exp2(-x*log2(e))) — verified passing (round 3).
__device__ __forceinline__ float silu_f(float x) {
    float e = __builtin_amdgcn_exp2f(-1.44269504088896f * x);
    return x * __builtin_amdgcn_rcpf(1.0f + e);
}
// software RNE f32->bf16 (verified). NOTE: v_cvt_pk_bf16_f32 inline asm
// produced NaN garbage on this toolchain (round 1/2) — do not reintroduce.
// NOTE (round 10): fp8-e4m3 ew interface fails absmax (0.094 > 0.085) —
// interface must stay bf16.
__device__ __forceinline__ unsigned short f2bf(float x) {
    __hip_bfloat16 h = __float2bfloat16(x);
    return *reinterpret_cast<unsigned short*>(&h);
}
__device__ __forceinline__ float bf2f(unsigned short u) {
    __hip_bfloat16 h;
    *reinterpret_cast<unsigned short*>(&h) = u;
    return __bfloat162float(h);
}

// ---------------- merged pre-pass (R11 best config) -------------------------
// blocks [0, 5000): node_in  (fvb + out = c_s*m)
// blocks [5000, 6250): edge-dst histogram
// blocks [6250, 6394): W2/W1 bf16 transpose prep
__global__ __launch_bounds__(256) void k_pre(
    const float* __restrict__ ni, const float* __restrict__ attr,
    const float* __restrict__ deg,
    const float* __restrict__ Wli0, const float* __restrict__ Wli1,
    const float* __restrict__ Wlm0, const float* __restrict__ Wlm1,
    ushort4* __restrict__ fvb, float* __restrict__ out,
    const int* __restrict__ edst, int* __restrict__ hist,
    const float* __restrict__ W2, const float* __restrict__ W1,
    unsigned short* __restrict__ w2t, unsigned short* __restrict__ w1t)
{
    __shared__ float raw[4][256];
    if (blockIdx.x < N_NODES / 4) {
        const int wave = threadIdx.x >> 6;
        const int lane = threadIdx.x & 63;
        const int n = blockIdx.x * 4 + wave;

        const float* row = ni + (size_t)n * 256;
        raw[wave][lane      ] = row[lane      ];
        raw[wave][lane + 64 ] = row[lane + 64 ];
        raw[wave][lane + 128] = row[lane + 128];
        raw[wave][lane + 192] = row[lane + 192];
        __syncthreads();

        float f0 = 0.f, m0 = 0.f;
        float f1x = 0.f, f1y = 0.f, f1z = 0.f;
        float m1x = 0.f, m1y = 0.f, m1z = 0.f;
        #pragma unroll 4
        for (int t = 0; t < 64; ++t) {
            float xs  = raw[wave][t];
            float xv0 = raw[wave][64 + t*3    ];
            float xv1 = raw[wave][64 + t*3 + 1];
            float xv2 = raw[wave][64 + t*3 + 2];
            float a0 = Wli0[t*64 + lane];
            float a1 = Wli1[t*64 + lane];
            float b0 = Wlm0[t*64 + lane];
            float b1 = Wlm1[t*64 + lane];
            f0  += xs  * a0;   m0  += xs  * b0;
            f1x += xv0 * a1;   f1y += xv1 * a1;   f1z += xv2 * a1;
            m1x += xv0 * b1;   m1y += xv1 * b1;   m1z += xv2 * b1;
        }

        const float a   = attr[n] * INV64;
        const float dis = 1.0f / sqrtf(deg[n]);
        const float fa  = a * dis;

        ushort4 pk;
        pk.x = f2bf(f0  * fa);
        pk.y = f2bf(f1x * fa);
        pk.z = f2bf(f1y * fa);
        pk.w = f2bf(f1z * fa);
        fvb[(size_t)n * 64 + lane] = pk;

        float* orow = out + (size_t)n * 256;
        orow[lane] = C_S * m0 * a;
        orow[64 + lane*3    ] = C_S * m1x * a;
        orow[64 + lane*3 + 1] = C_S * m1y * a;
        orow[64 + lane*3 + 2] = C_S * m1z * a;
    } else if (blockIdx.x < N_NODES / 4 + N_EDGES / 256) {
        const int e = (blockIdx.x - N_NODES / 4) * 256 + threadIdx.x;
        atomicAdd(&hist[edst[e]], 1);
    } else {
        const int i = (blockIdx.x - N_NODES / 4 - N_EDGES / 256) * 256
                    + threadIdx.x;
        if (i < 32768) {
            const int n = i >> 7, k = i & 127;
            w2t[i] = (k < 100) ? f2bf(W2[k*256 + n] * SC2) : (unsigned short)0;
        } else if (i < 32768 + 3584) {
            const int j = i - 32768;
            const int n = j >> 5, k = j & 31;
            w1t[j] = (k < 10 && n < 100) ? f2bf(W1[k*100 + n] * INV1)
                                         : (unsigned short)0;
        }
    }
}

// ---------------- scan: shuffle-based, 2 barriers (was 20) -----------------
// Per thread: cache 20 hist values in regs (one pass), wave shfl_up scan,
// 16 wave-totals via LDS, wave-0 scans those, write-out from regs.
__global__ __launch_bounds__(1024) void k_scan(const int* __restrict__ hist,
                                               int* __restrict__ starts,
                                               int* __restrict__ cursor) {
    __shared__ int wtot[16];
    __shared__ int woff[16];
    const int t    = threadIdx.x;
    const int lane = t & 63;
    const int w    = t >> 6;
    const int C    = 20;
    const int base = t * C;

    int h[20];
    int s = 0;
    #pragma unroll
    for (int i = 0; i < C; ++i) {
        const int idx = base + i;
        h[i] = (idx < N_NODES) ? hist[idx] : 0;
        s += h[i];
    }

    // wave-inclusive scan of s (6 shfl_up steps, no barriers)
    int incl = s;
    #pragma unroll
    for (int off = 1; off < 64; off <<= 1) {
        int v = __shfl_up(incl, off);
        if (lane >= off) incl += v;
    }
    if (lane == 63) wtot[w] = incl;
    __syncthreads();

    if (w == 0) {
        int ws = (lane < 16) ? wtot[lane] : 0;
        int wincl = ws;
        #pragma unroll
        for (int off = 1; off < 16; off <<= 1) {
            int v = __shfl_up(wincl, off);
            if (lane >= off) wincl += v;
        }
        if (lane < 16) woff[lane] = wincl - ws;   // exclusive prefix
    }
    __syncthreads();

    int run = woff[w] + (incl - s);   // exclusive prefix for this thread
    #pragma unroll
    for (int i = 0; i < C; ++i) {
        const int idx = base + i;
        if (idx < N_NODES) {
            starts[idx] = run;
            cursor[idx] = run;
            run += h[i];
        }
    }
    if (t == 1023) starts[N_NODES] = N_EDGES;
}

// ---------------- merged mid-pass: scatter (sort) || edge-MLP (unsorted) ----
// R11-verbatim: ew computed in ORIGINAL edge order (depends only on elen);
//   blocks [0, 1250):    scatter — sort esrc/eattr/eidx by dst
//   blocks [1250, 3750): MLP     — MFMA pipeline, elen read f32
// k_gather indexes ew rows via eidx_s (row reads stay 64-lane coalesced).

// load one edge's elen slice as bf16 short8: lane-q covers elems q*8..q*8+7;
// row is 10 floats, so q=1 has elems 8,9 valid + 6 zeros.
__device__ __forceinline__ short8 ld_elen8(const float* __restrict__ elen,
                                           int e, int q)
{
    const float* er = elen + (size_t)e * 10 + q * 8;
    float v0 = er[0], v1 = er[1];
    float v2 = 0.f, v3 = 0.f, v4 = 0.f, v5 = 0.f, v6 = 0.f, v7 = 0.f;
    if (q == 0) {
        v2 = er[2]; v3 = er[3]; v4 = er[4];
        v5 = er[5]; v6 = er[6]; v7 = er[7];
    }
    short8 r;
    r[0] = (short)f2bf(v0); r[1] = (short)f2bf(v1);
    r[2] = (short)f2bf(v2); r[3] = (short)f2bf(v3);
    r[4] = (short)f2bf(v4); r[5] = (short)f2bf(v5);
    r[6] = (short)f2bf(v6); r[7] = (short)f2bf(v7);
    return r;
}

__device__ __forceinline__ void p2_ldB(const unsigned short* __restrict__ w2t,
                                       int ntA, int m15, int q,
                                       short8* BA, short8* BB)
{
    const unsigned short* bpA = w2t + ((size_t)(ntA*16 + m15) << 7);
    const unsigned short* bpB = w2t + ((size_t)((ntA + 4)*16 + m15) << 7);
    #pragma unroll
    for (int s = 0; s < 4; ++s) {
        BA[s] = *(const short8*)(bpA + s*32 + q*8);
        BB[s] = *(const short8*)(bpB + s*32 + q*8);
    }
}

__device__ __forceinline__ void p2_mfma_store(
    const short8* A0, const short8* A1,
    const short8* BA, const short8* BB,
    unsigned int* __restrict__ dstp,
    int e0, int eb, int m15, int q, int nt4)
{
    f32x4 ca0 = {0.f,0.f,0.f,0.f}, ca1 = {0.f,0.f,0.f,0.f};
    f32x4 cb0 = {0.f,0.f,0.f,0.f}, cb1 = {0.f,0.f,0.f,0.f};
    #pragma unroll
    for (int s = 0; s < 4; ++s) {
        ca0 = __builtin_amdgcn_mfma_f32_16x16x32_bf16(BA[s], A0[s], ca0, 0, 0, 0);
        ca1 = __builtin_amdgcn_mfma_f32_16x16x32_bf16(BA[s], A1[s], ca1, 0, 0, 0);
        cb0 = __builtin_amdgcn_mfma_f32_16x16x32_bf16(BB[s], A0[s], cb0, 0, 0, 0);
        cb1 = __builtin_amdgcn_mfma_f32_16x16x32_bf16(BB[s], A1[s], cb1, 0, 0, 0);
    }
    uint4 U0, U1;
    U0.x = (unsigned int)f2bf(ca0[0]) | ((unsigned int)f2bf(cb0[0]) << 16);
    U0.y = (unsigned int)f2bf(ca0[1]) | ((unsigned int)f2bf(cb0[1]) << 16);
    U0.z = (unsigned int)f2bf(ca0[2]) | ((unsigned int)f2bf(cb0[2]) << 16);
    U0.w = (unsigned int)f2bf(ca0[3]) | ((unsigned int)f2bf(cb0[3]) << 16);
    U1.x = (unsigned int)f2bf(ca1[0]) | ((unsigned int)f2bf(cb1[0]) << 16);
    U1.y = (unsigned int)f2bf(ca1[1]) | ((unsigned int)f2bf(cb1[1]) << 16);
    U1.z = (unsigned int)f2bf(ca1[2]) | ((unsigned int)f2bf(cb1[2]) << 16);
    U1.w = (unsigned int)f2bf(ca1[3]) | ((unsigned int)f2bf(cb1[3]) << 16);
    *(uint4*)(dstp + (size_t)(e0 + eb      + m15)*64 + nt4*16 + q*4) = U0;
    *(uint4*)(dstp + (size_t)(e0 + eb + 16 + m15)*64 + nt4*16 + q*4) = U1;
}

__global__ __launch_bounds__(256, 4) void k_mid(
    const int* __restrict__ esrc, const int* __restrict__ edst,
    const float4* __restrict__ eattr4, const float* __restrict__ elen,
    int* __restrict__ cursor, int* __restrict__ esrc_s,
    int* __restrict__ eidx_s, float4* __restrict__ eattrs,
    const unsigned short* __restrict__ w1t,
    const unsigned short* __restrict__ w2t,
    unsigned int* __restrict__ ewAB,
    unsigned int* __restrict__ ewCD)
{
    __shared__ unsigned short Hs[128 * 136];   // [edge][hid] stride 136

    if (blockIdx.x < N_EDGES / 256) {
        // ---------------- scatter branch -----------------------------------
        const int e = blockIdx.x * 256 + threadIdx.x;
        const int p = atomicAdd(&cursor[edst[e]], 1);
        esrc_s[p] = esrc[e];
        eidx_s[p] = e;
        eattrs[p] = eattr4[e];
        return;
    }

    // ---------------- MLP branch (unsorted edges) --------------------------
    const int t    = threadIdx.x;
    const int w    = t >> 6;
    const int lane = t & 63;
    const int m15  = lane & 15;
    const int q    = lane >> 4;
    const int eb   = w * 32;
    const int e0   = (blockIdx.x - N_EDGES / 256) * 128;

    short8 xa0 = ld_elen8(elen, e0 + eb      + m15, q);
    short8 xa1 = ld_elen8(elen, e0 + eb + 16 + m15, q);

    short8 bw[7];
    #pragma unroll
    for (int nt = 0; nt < 7; ++nt)
        bw[nt] = *(const short8*)(w1t + (nt*16 + m15)*32 + q*8);

    short8 Ba[4], Bb[4], Ca[4], Cb[4];
    p2_ldB(w2t, 0 /*ntA(idx=0)*/, m15, q, Ba, Bb);

    {   // zero hid 112..127 of all 32 rows of this wave
        const int r = eb + (lane >> 1);
        const int c = 112 + (lane & 1) * 8;
        short8 z = {0,0,0,0,0,0,0,0};
        *(short8*)&Hs[r*136 + c] = z;
    }

    // ---- phase 1: D[hid][edge]; lane owns hid nt*16+q*4+{0..3} of edge m15
    #pragma unroll
    for (int nt = 0; nt < 7; ++nt) {
        f32x4 z4 = {0.f, 0.f, 0.f, 0.f};
        f32x4 h0 = __builtin_amdgcn_mfma_f32_16x16x32_bf16(bw[nt], xa0, z4, 0, 0, 0);
        f32x4 h1 = __builtin_amdgcn_mfma_f32_16x16x32_bf16(bw[nt], xa1, z4, 0, 0, 0);
        uint2 d0, d1;
        d0.x = (unsigned int)f2bf(silu_f(h0[0])) | ((unsigned int)f2bf(silu_f(h0[1])) << 16);
        d0.y = (unsigned int)f2bf(silu_f(h0[2])) | ((unsigned int)f2bf(silu_f(h0[3])) << 16);
        d1.x = (unsigned int)f2bf(silu_f(h1[0])) | ((unsigned int)f2bf(silu_f(h1[1])) << 16);
        d1.y = (unsigned int)f2bf(silu_f(h1[2])) | ((unsigned int)f2bf(silu_f(h1[3])) << 16);
        *(uint2*)&Hs[(eb      + m15)*136 + nt*16 + q*4] = d0;
        *(uint2*)&Hs[(eb + 16 + m15)*136 + nt*16 + q*4] = d1;
    }
    // same-wave RAW on Hs -> compiler lgkmcnt, no barrier

    short8 A0[4], A1[4];   // H frags: lane -> (edge m15, k = s*32+q*8+j)
    #pragma unroll
    for (int s = 0; s < 4; ++s) {
        A0[s] = *(const short8*)&Hs[(eb      + m15)*136 + s*32 + q*8];
        A1[s] = *(const short8*)&Hs[(eb + 16 + m15)*136 + s*32 + q*8];
    }

    // ---- phase 2, pipelined: idx = 0..7; grp = idx>>2, nt4 = idx&3,
    // ntA = grp*8 + nt4, dst = grp ? ewCD : ewAB.
    #pragma unroll
    for (int ii = 0; ii < 4; ++ii) {
        const int i0 = 2*ii, i1 = 2*ii + 1;
        const int ntA1 = ((i1 >> 2) * 8) + (i1 & 3);
        p2_ldB(w2t, ntA1, m15, q, Ca, Cb);                     // prefetch odd
        {
            unsigned int* dst0 = (i0 >> 2) ? ewCD : ewAB;
            p2_mfma_store(A0, A1, Ba, Bb, dst0, e0, eb, m15, q, i0 & 3);
        }
        if (ii < 3) {
            const int i2 = i0 + 2;
            const int ntA2 = ((i2 >> 2) * 8) + (i2 & 3);
            p2_ldB(w2t, ntA2, m15, q, Ba, Bb);                 // prefetch next even
        }
        {
            unsigned int* dst1 = (i1 >> 2) ? ewCD : ewAB;
            p2_mfma_store(A0, A1, Ca, Cb, dst1, e0, eb, m15, q, i1 & 3);
        }
    }
}

// ---------------- per-dst gather + fused W_lo GEMM + epilogue ---------------
__global__ __launch_bounds__(256) void k_gather(
    const int* __restrict__ starts, const int* __restrict__ esrc_s,
    const int* __restrict__ eidx_s,
    const float4* __restrict__ eattrs,
    const unsigned int* __restrict__ ewAB,
    const unsigned int* __restrict__ ewCD,
    const ushort4* __restrict__ fvb,
    const float* __restrict__ attr, const float* __restrict__ deg,
    const float* __restrict__ Wlo0, const float* __restrict__ Wlo1,
    float* __restrict__ out)
{
    __shared__ float sm[4][512];
    const int wave = threadIdx.x >> 6;
    const int lane = threadIdx.x & 63;
    const int n = blockIdx.x * 4 + wave;

    const int beg = starts[n], end = starts[n + 1];
    float sA=0.f, sB=0.f;
    float vA0=0.f, vA1=0.f, vA2=0.f;
    float vB0=0.f, vB1=0.f, vB2=0.f;

    for (int base = beg; base < end; base += 64) {
        const int cnt = min(64, end - base);
        int    srcv = 0, eidxv = 0;
        float4 eav  = make_float4(0.f, 0.f, 0.f, 0.f);
        if (lane < cnt) {
            srcv  = esrc_s[base + lane];
            eidxv = eidx_s[base + lane];
            eav   = eattrs[base + lane];
        }
        #pragma unroll 2
        for (int j = 0; j < cnt; ++j) {
            const int   src = __shfl(srcv, j);
            const int   ei  = __shfl(eidxv, j);
            const float y0  = __shfl(eav.x, j);
            const float y10 = __shfl(eav.y, j);
            const float y11 = __shfl(eav.z, j);
            const float y12 = __shfl(eav.w, j);

            const unsigned int uab = ewAB[(size_t)ei*64 + lane];
            const unsigned int ucd = ewCD[(size_t)ei*64 + lane];
            const float wa = bf2f((unsigned short)(uab & 0xFFFFu));
            const float wb = bf2f((unsigned short)(uab >> 16));
            const float wc = bf2f((unsigned short)(ucd & 0xFFFFu));
            const float wd = bf2f((unsigned short)(ucd >> 16));

            const ushort4 g4 = fvb[(size_t)src * 64 + lane];
            const float g0  = bf2f(g4.x);
            const float g10 = bf2f(g4.y);
            const float g11 = bf2f(g4.z);
            const float g12 = bf2f(g4.w);

            const float dotv = g10*y10 + g11*y11 + g12*y12;
            sA += wa * g0 * y0;
            sB += wb * dotv;
            const float t0 = wc * g0;
            vA0 += t0 * y10;  vA1 += t0 * y11;  vA2 += t0 * y12;
            const float t1 = wd * y0;
            vB0 += t1 * g10;  vB1 += t1 * g11;  vB2 += t1 * g12;
        }
    }

    const float dis = 1.0f / sqrtf(deg[n]);
    sm[wave][lane            ] = sA * dis;
    sm[wave][64  + lane      ] = sB * IS3 * dis;
    sm[wave][128 + lane      ] = vA0 * dis;
    sm[wave][128 + 64 + lane ] = vB0 * dis;
    sm[wave][256 + lane      ] = vA1 * dis;
    sm[wave][256 + 64 + lane ] = vB1 * dis;
    sm[wave][384 + lane      ] = vA2 * dis;
    sm[wave][384 + 64 + lane ] = vB2 * dis;
    __syncthreads();

    float o0=0.f, o1x=0.f, o1y=0.f, o1z=0.f;
    #pragma unroll 4
    for (int c = 0; c < 128; ++c) {
        const float w0 = Wlo0[c*64 + lane];
        const float w1 = Wlo1[c*64 + lane];
        o0  += sm[wave][c]         * w0;
        o1x += sm[wave][128 + c]   * w1;
        o1y += sm[wave][256 + c]   * w1;
        o1z += sm[wave][384 + c]   * w1;
    }

    const float a = attr[n] * INVLO;
    float* orow = out + (size_t)n * 256;
    orow[lane] += C_X * o0 * a;
    orow[64 + lane*3    ] += C_X * o1x * a;
    orow[64 + lane*3 + 1] += C_X * o1y * a;
    orow[64 + lane*3 + 2] += C_X * o1z * a;
}

// ======================= fallback (round-1) path ============================
__global__ __launch_bounds__(256) void k_node_in_legacy(
    const float* __restrict__ ni, const float* __restrict__ attr,
    const float* __restrict__ deg,
    const float* __restrict__ Wli0, const float* __restrict__ Wli1,
    const float* __restrict__ Wlm0, const float* __restrict__ Wlm1,
    float* __restrict__ f, float* __restrict__ out)
{
    __shared__ float raw[4][256];
    const int wave = threadIdx.x >> 6;
    const int lane = threadIdx.x & 63;
    const int n = blockIdx.x * 4 + wave;

    const float* row = ni + (size_t)n * 256;
    raw[wave][lane      ] = row[lane      ];
    raw[wave][lane + 64 ] = row[lane + 64 ];
    raw[wave][lane + 128] = row[lane + 128];
    raw[wave][lane + 192] = row[lane + 192];
    __syncthreads();

    float f0 = 0.f, m0 = 0.f;
    float f1x = 0.f, f1y = 0.f, f1z = 0.f;
    float m1x = 0.f, m1y = 0.f, m1z = 0.f;
    for (int t = 0; t < 64; ++t) {
        float xs  = raw[wave][t];
        float xv0 = raw[wave][64 + t*3    ];
        float xv1 = raw[wave][64 + t*3 + 1];
        float xv2 = raw[wave][64 + t*3 + 2];
        float a0 = Wli0[t*64 + lane];
        float a1 = Wli1[t*64 + lane];
        float b0 = Wlm0[t*64 + lane];
        float b1 = Wlm1[t*64 + lane];
        f0  += xs  * a0;   m0  += xs  * b0;
        f1x += xv0 * a1;   f1y += xv1 * a1;   f1z += xv2 * a1;
        m1x += xv0 * b1;   m1y += xv1 * b1;   m1z += xv2 * b1;
    }

    const float a   = attr[n] * INV64;
    const float dis = 1.0f / sqrtf(deg[n]);
    const float fa  = a * dis;

    float* fr = f + (size_t)n * 256;
    fr[lane      ] = f0  * fa;
    fr[64  + lane] = f1x * fa;
    fr[128 + lane] = f1y * fa;
    fr[192 + lane] = f1z * fa;

    float* orow = out + (size_t)n * 256;
    orow[lane] = C_S * m0 * a;
    orow[64 + lane*3    ] = C_S * m1x * a;
    orow[64 + lane*3 + 1] = C_S * m1y * a;
    orow[64 + lane*3 + 2] = C_S * m1z * a;
}

__global__ __launch_bounds__(256) void k_edge_legacy(
    const float* __restrict__ eattr, const float* __restrict__ elen,
    const float* __restrict__ W1, const float* __restrict__ W2,
    const int* __restrict__ esrc, const int* __restrict__ edst,
    const float* __restrict__ f, float* __restrict__ acc)
{
    __shared__ float hsh[4][104];
    const int wave = threadIdx.x >> 6;
    const int lane = threadIdx.x & 63;
    const int e = blockIdx.x * 4 + wave;

    const float* el = elen + (size_t)e * 10;
    float elr[10];
    #pragma unroll
    for (int b = 0; b < 10; ++b) elr[b] = el[b];

    float a1 = 0.f;
    #pragma unroll
    for (int b = 0; b < 10; ++b) a1 += elr[b] * W1[b*100 + lane];
    hsh[wave][lane] = silu_f(a1 * INV1);
    if (lane < 36) {
        float a2 = 0.f;
        #pragma unroll
        for (int b = 0; b < 10; ++b) a2 += elr[b] * W1[b*100 + 64 + lane];
        hsh[wave][64 + lane] = silu_f(a2 * INV1);
    }
    __syncthreads();

    float wa = 0.f, wb = 0.f, wc = 0.f, wd = 0.f;
    for (int j = 0; j < 100; ++j) {
        float hj = hsh[wave][j];
        const float* wr = W2 + j*256;
        wa += hj * wr[lane      ];
        wb += hj * wr[64  + lane];
        wc += hj * wr[128 + lane];
        wd += hj * wr[192 + lane];
    }
    wa *= SC2; wb *= SC2; wc *= SC2; wd *= SC2;

    const int src = esrc[e];
    const int dst = edst[e];
    const float y0  = eattr[e*4 + 0];
    const float y10 = eattr[e*4 + 1];
    const float y11 = eattr[e*4 + 2];
    const float y12 = eattr[e*4 + 3];

    const float* fr = f + (size_t)src * 256;
    const float g0  = fr[lane      ];
    const float g10 = fr[64  + lane];
    const float g11 = fr[128 + lane];
    const float g12 = fr[192 + lane];

    const float dotv = g10*y10 + g11*y11 + g12*y12;

    float* ar = acc + (size_t)dst * 512;
    atomicAdd(ar + lane,                  wa * g0 * y0);
    atomicAdd(ar + 64 + lane,             wb * dotv * IS3);
    atomicAdd(ar + 128 +   0 + lane,      wc * g0 * y10);
    atomicAdd(ar + 128 + 128 + lane,      wc * g0 * y11);
    atomicAdd(ar + 128 + 256 + lane,      wc * g0 * y12);
    atomicAdd(ar + 128 +   0 + 64 + lane, wd * g10 * y0);
    atomicAdd(ar + 128 + 128 + 64 + lane, wd * g11 * y0);
    atomicAdd(ar + 128 + 256 + 64 + lane, wd * g12 * y0);
}

__global__ __launch_bounds__(256) void k_node_out_legacy(
    const float* __restrict__ acc, const float* __restrict__ attr,
    const float* __restrict__ deg, const float* __restrict__ Wlo0,
    const float* __restrict__ Wlo1, float* __restrict__ out)
{
    __shared__ float sm[4][512];
    const int wave = threadIdx.x >> 6;
    const int lane = threadIdx.x & 63;
    const int n = blockIdx.x * 4 + wave;

    const float dis = 1.0f / sqrtf(deg[n]);
    const float* ar = acc + (size_t)n * 512;
    for (int i = lane; i < 512; i += 64) sm[wave][i] = ar[i] * dis;
    __syncthreads();

    float o0 = 0.f, o1x = 0.f, o1y = 0.f, o1z = 0.f;
    for (int c = 0; c < 128; ++c) {
        float w0 = Wlo0[c*64 + lane];
        float w1 = Wlo1[c*64 + lane];
        o0  += sm[wave][c]        * w0;
        o1x += sm[wave][128 + c]  * w1;
        o1y += sm[wave][256 + c]  * w1;
        o1z += sm[wave][384 + c]  * w1;
    }

    const float a = attr[n] * INVLO;
    float* orow = out + (size_t)n * 256;
    orow[lane] += C_X * o0 * a;
    orow[64 + lane*3    ] += C_X * o1x * a;
    orow[64 + lane*3 + 1] += C_X * o1y * a;
    orow[64 + lane*3 + 2] += C_X * o1z * a;
}

// ============================================================================
extern "C" void kernel_launch(void* const* d_in, const int* in_sizes, int n_in,
                              void* d_out, int out_size, void* d_ws, size_t ws_size,
                              hipStream_t stream) {
    const float* ni    = (const float*)d_in[0];
    const float* attr  = (const float*)d_in[1];
    const float* deg   = (const float*)d_in[2];
    const float* eattr = (const float*)d_in[3];
    const float* elen  = (const float*)d_in[4];
    const float* Wli0  = (const float*)d_in[5];
    const float* Wli1  = (const float*)d_in[6];
    const float* Wlm0  = (const float*)d_in[7];
    const float* Wlm1  = (const float*)d_in[8];
    const float* Wm1   = (const float*)d_in[9];
    const float* Wm2   = (const float*)d_in[10];
    const float* Wlo0  = (const float*)d_in[11];
    const float* Wlo1  = (const float*)d_in[12];
    const int*   esrc  = (const int*)d_in[13];
    const int*   edst  = (const int*)d_in[14];

    float* out = (float*)d_out;

    // ws layout (fast path), 16 B-aligned sections
    char* wsb = (char*)d_ws;
    size_t off = 0;
    ushort4* fvb = (ushort4*)(wsb + off);               off += (size_t)N_NODES * 64 * 8;    // 10.24 MB
    unsigned int* ewAB = (unsigned int*)(wsb + off);    off += (size_t)N_EDGES * 64 * 4;    // 81.92 MB
    unsigned int* ewCD = (unsigned int*)(wsb + off);    off += (size_t)N_EDGES * 64 * 4;    // 81.92 MB
    float4* eattrs = (float4*)(wsb + off);              off += (size_t)N_EDGES * 16;        // 5.12 MB
    int* esrc_s = (int*)(wsb + off);                    off += (size_t)N_EDGES * 4;         // 1.28 MB
    int* eidx_s = (int*)(wsb + off);                    off += (size_t)N_EDGES * 4;         // 1.28 MB
    unsigned short* w2t = (unsigned short*)(wsb + off); off += 32768 * 2;
    unsigned short* w1t = (unsigned short*)(wsb + off); off += 3584 * 2;
    int* starts = (int*)(wsb + off);                    off += (size_t)(N_NODES + 4) * 4;
    int* hist   = (int*)(wsb + off);                    off += (size_t)N_NODES * 4;
    int* cursor = (int*)(wsb + off);                    off += (size_t)N_NODES * 4;
    const size_t need_fast = off;

    if (ws_size >= need_fast) {
        hipMemsetAsync(hist, 0, (size_t)N_NODES * sizeof(int), stream);
        k_pre    <<<N_NODES / 4 + N_EDGES / 256 + 144, 256, 0, stream>>>(
                     ni, attr, deg, Wli0, Wli1, Wlm0, Wlm1, fvb, out,
                     edst, hist, Wm2, Wm1, w2t, w1t);
        k_scan   <<<1, 1024, 0, stream>>>(hist, starts, cursor);
        k_mid    <<<N_EDGES / 256 + N_EDGES / 128, 256, 0, stream>>>(
                     esrc, edst, (const float4*)eattr, elen,
                     cursor, esrc_s, eidx_s, eattrs,
                     w1t, w2t, ewAB, ewCD);
        k_gather <<<N_NODES / 4, 256, 0, stream>>>(starts, esrc_s, eidx_s,
                                                   eattrs, ewAB, ewCD,
                                                   fvb, attr, deg,
                                                   Wlo0, Wlo1, out);
    } else {
        // fallback: round-1 atomic path (61.4 MB scratch)
        float* f   = (float*)d_ws;
        float* acc = f + (size_t)N_NODES * 256;
        hipMemsetAsync(acc, 0, (size_t)N_NODES * 512 * sizeof(float), stream);
        k_node_in_legacy<<<N_NODES / 4, 256, 0, stream>>>(ni, attr, deg, Wli0, Wli1,
                                                          Wlm0, Wlm1, f, out);
        k_edge_legacy<<<N_EDGES / 4, 256, 0, stream>>>(eattr, elen, Wm1, Wm2,
                                                       esrc, edst, f, acc);
        k_node_out_legacy<<<N_NODES / 4, 256, 0, stream>>>(acc, attr, deg,
                                                           Wlo0, Wlo1, out);
    }
}

// Round 15
// 366.962 us; speedup vs baseline: 1.0633x; 1.0166x over previous
//
#include <hip/hip_runtime.h>
#include <hip/hip_bf16.h>
#include <math.h>

#define N_NODES 20000
#define N_EDGES 320000

#define INV1   0.31622776601683794f   // 1/sqrt(10)
#define SC2    0.1f                   // 1/sqrt(100)
#define IS3    0.5773502691896258f    // 1/sqrt(3)
#define C_S    0.3826834323650898f    // sin(pi/8)
#define C_X    0.9238795325112867f    // cos(pi/8)
#define INV64  0.125f                 // 1/sqrt(64)
#define INVLO  0.08838834764831845f   // 1/sqrt(128)

typedef short     short8 __attribute__((ext_vector_type(8)));
typedef float     f32x4  __attribute__((ext_vector_type(4)));

// fast silu: x * rcp(1 + exp2(-x*log2(e))) — verified passing (round 3).
__device__ __forceinline__ float silu_f(float x) {
    float e = __builtin_amdgcn_exp2f(-1.44269504088896f * x);
    return x * __builtin_amdgcn_rcpf(1.0f + e);
}
// software RNE f32->bf16 (verified). NOTE: v_cvt_pk_bf16_f32 inline asm
// produced NaN garbage on this toolchain (round 1/2) — do not reintroduce.
// NOTE (round 10): fp8-e4m3 ew interface fails absmax (0.094 > 0.085) —
// interface must stay bf16.
__device__ __forceinline__ unsigned short f2bf(float x) {
    __hip_bfloat16 h = __float2bfloat16(x);
    return *reinterpret_cast<unsigned short*>(&h);
}
__device__ __forceinline__ float bf2f(unsigned short u) {
    __hip_bfloat16 h;
    *reinterpret_cast<unsigned short*>(&h) = u;
    return __bfloat162float(h);
}

// ---------------- merged pre-pass ------------------------------------------
// Round-15: node_in processes 2 NODES PER WAVE (weight loads amortized 2x:
// 1.28 GB -> 640 MB L2 weight traffic). blocks:
//   [0, 2500):        node_in — 8 nodes/block (4 waves x 2 nodes)
//   [2500, 3750):     edge-dst histogram
//   [3750, 3894):     W2/W1 bf16 transpose prep
__global__ __launch_bounds__(256) void k_pre(
    const float* __restrict__ ni, const float* __restrict__ attr,
    const float* __restrict__ deg,
    const float* __restrict__ Wli0, const float* __restrict__ Wli1,
    const float* __restrict__ Wlm0, const float* __restrict__ Wlm1,
    ushort4* __restrict__ fvb, float* __restrict__ out,
    const int* __restrict__ edst, int* __restrict__ hist,
    const float* __restrict__ W2, const float* __restrict__ W1,
    unsigned short* __restrict__ w2t, unsigned short* __restrict__ w1t)
{
    __shared__ float raw[4][512];
    if (blockIdx.x < N_NODES / 8) {
        const int wave = threadIdx.x >> 6;
        const int lane = threadIdx.x & 63;
        const int n0 = blockIdx.x * 8 + wave * 2;
        const int n1 = n0 + 1;

        const float* row0 = ni + (size_t)n0 * 256;
        const float* row1 = ni + (size_t)n1 * 256;
        raw[wave][lane      ] = row0[lane      ];
        raw[wave][lane + 64 ] = row0[lane + 64 ];
        raw[wave][lane + 128] = row0[lane + 128];
        raw[wave][lane + 192] = row0[lane + 192];
        raw[wave][256 + lane      ] = row1[lane      ];
        raw[wave][256 + lane + 64 ] = row1[lane + 64 ];
        raw[wave][256 + lane + 128] = row1[lane + 128];
        raw[wave][256 + lane + 192] = row1[lane + 192];
        __syncthreads();

        float f0a = 0.f, m0a = 0.f;
        float f1xa = 0.f, f1ya = 0.f, f1za = 0.f;
        float m1xa = 0.f, m1ya = 0.f, m1za = 0.f;
        float f0b = 0.f, m0b = 0.f;
        float f1xb = 0.f, f1yb = 0.f, f1zb = 0.f;
        float m1xb = 0.f, m1yb = 0.f, m1zb = 0.f;
        #pragma unroll 4
        for (int t = 0; t < 64; ++t) {
            const float a0 = Wli0[t*64 + lane];
            const float a1 = Wli1[t*64 + lane];
            const float b0 = Wlm0[t*64 + lane];
            const float b1 = Wlm1[t*64 + lane];

            float xs  = raw[wave][t];
            float xv0 = raw[wave][64 + t*3    ];
            float xv1 = raw[wave][64 + t*3 + 1];
            float xv2 = raw[wave][64 + t*3 + 2];
            f0a  += xs  * a0;   m0a  += xs  * b0;
            f1xa += xv0 * a1;   f1ya += xv1 * a1;   f1za += xv2 * a1;
            m1xa += xv0 * b1;   m1ya += xv1 * b1;   m1za += xv2 * b1;

            float ys  = raw[wave][256 + t];
            float yv0 = raw[wave][256 + 64 + t*3    ];
            float yv1 = raw[wave][256 + 64 + t*3 + 1];
            float yv2 = raw[wave][256 + 64 + t*3 + 2];
            f0b  += ys  * a0;   m0b  += ys  * b0;
            f1xb += yv0 * a1;   f1yb += yv1 * a1;   f1zb += yv2 * a1;
            m1xb += yv0 * b1;   m1yb += yv1 * b1;   m1zb += yv2 * b1;
        }

        {
            const float a   = attr[n0] * INV64;
            const float dis = 1.0f / sqrtf(deg[n0]);
            const float fa  = a * dis;
            ushort4 pk;
            pk.x = f2bf(f0a  * fa);
            pk.y = f2bf(f1xa * fa);
            pk.z = f2bf(f1ya * fa);
            pk.w = f2bf(f1za * fa);
            fvb[(size_t)n0 * 64 + lane] = pk;
            float* orow = out + (size_t)n0 * 256;
            orow[lane] = C_S * m0a * a;
            orow[64 + lane*3    ] = C_S * m1xa * a;
            orow[64 + lane*3 + 1] = C_S * m1ya * a;
            orow[64 + lane*3 + 2] = C_S * m1za * a;
        }
        {
            const float a   = attr[n1] * INV64;
            const float dis = 1.0f / sqrtf(deg[n1]);
            const float fa  = a * dis;
            ushort4 pk;
            pk.x = f2bf(f0b  * fa);
            pk.y = f2bf(f1xb * fa);
            pk.z = f2bf(f1yb * fa);
            pk.w = f2bf(f1zb * fa);
            fvb[(size_t)n1 * 64 + lane] = pk;
            float* orow = out + (size_t)n1 * 256;
            orow[lane] = C_S * m0b * a;
            orow[64 + lane*3    ] = C_S * m1xb * a;
            orow[64 + lane*3 + 1] = C_S * m1yb * a;
            orow[64 + lane*3 + 2] = C_S * m1zb * a;
        }
    } else if (blockIdx.x < N_NODES / 8 + N_EDGES / 256) {
        const int e = (blockIdx.x - N_NODES / 8) * 256 + threadIdx.x;
        atomicAdd(&hist[edst[e]], 1);
    } else {
        const int i = (blockIdx.x - N_NODES / 8 - N_EDGES / 256) * 256
                    + threadIdx.x;
        if (i < 32768) {
            const int n = i >> 7, k = i & 127;
            w2t[i] = (k < 100) ? f2bf(W2[k*256 + n] * SC2) : (unsigned short)0;
        } else if (i < 32768 + 3584) {
            const int j = i - 32768;
            const int n = j >> 5, k = j & 31;
            w1t[j] = (k < 10 && n < 100) ? f2bf(W1[k*100 + n] * INV1)
                                         : (unsigned short)0;
        }
    }
}

// ---------------- scan: shuffle-based, 2 barriers (R14-verified) -----------
__global__ __launch_bounds__(1024) void k_scan(const int* __restrict__ hist,
                                               int* __restrict__ starts,
                                               int* __restrict__ cursor) {
    __shared__ int wtot[16];
    __shared__ int woff[16];
    const int t    = threadIdx.x;
    const int lane = t & 63;
    const int w    = t >> 6;
    const int C    = 20;
    const int base = t * C;

    int h[20];
    int s = 0;
    #pragma unroll
    for (int i = 0; i < C; ++i) {
        const int idx = base + i;
        h[i] = (idx < N_NODES) ? hist[idx] : 0;
        s += h[i];
    }

    int incl = s;
    #pragma unroll
    for (int off = 1; off < 64; off <<= 1) {
        int v = __shfl_up(incl, off);
        if (lane >= off) incl += v;
    }
    if (lane == 63) wtot[w] = incl;
    __syncthreads();

    if (w == 0) {
        int ws = (lane < 16) ? wtot[lane] : 0;
        int wincl = ws;
        #pragma unroll
        for (int off = 1; off < 16; off <<= 1) {
            int v = __shfl_up(wincl, off);
            if (lane >= off) wincl += v;
        }
        if (lane < 16) woff[lane] = wincl - ws;   // exclusive prefix
    }
    __syncthreads();

    int run = woff[w] + (incl - s);
    #pragma unroll
    for (int i = 0; i < C; ++i) {
        const int idx = base + i;
        if (idx < N_NODES) {
            starts[idx] = run;
            cursor[idx] = run;
            run += h[i];
        }
    }
    if (t == 1023) starts[N_NODES] = N_EDGES;
}

// ---------------- merged mid-pass: scatter (sort) || edge-MLP (unsorted) ----
// R11-verbatim.
__device__ __forceinline__ short8 ld_elen8(const float* __restrict__ elen,
                                           int e, int q)
{
    const float* er = elen + (size_t)e * 10 + q * 8;
    float v0 = er[0], v1 = er[1];
    float v2 = 0.f, v3 = 0.f, v4 = 0.f, v5 = 0.f, v6 = 0.f, v7 = 0.f;
    if (q == 0) {
        v2 = er[2]; v3 = er[3]; v4 = er[4];
        v5 = er[5]; v6 = er[6]; v7 = er[7];
    }
    short8 r;
    r[0] = (short)f2bf(v0); r[1] = (short)f2bf(v1);
    r[2] = (short)f2bf(v2); r[3] = (short)f2bf(v3);
    r[4] = (short)f2bf(v4); r[5] = (short)f2bf(v5);
    r[6] = (short)f2bf(v6); r[7] = (short)f2bf(v7);
    return r;
}

__device__ __forceinline__ void p2_ldB(const unsigned short* __restrict__ w2t,
                                       int ntA, int m15, int q,
                                       short8* BA, short8* BB)
{
    const unsigned short* bpA = w2t + ((size_t)(ntA*16 + m15) << 7);
    const unsigned short* bpB = w2t + ((size_t)((ntA + 4)*16 + m15) << 7);
    #pragma unroll
    for (int s = 0; s < 4; ++s) {
        BA[s] = *(const short8*)(bpA + s*32 + q*8);
        BB[s] = *(const short8*)(bpB + s*32 + q*8);
    }
}

__device__ __forceinline__ void p2_mfma_store(
    const short8* A0, const short8* A1,
    const short8* BA, const short8* BB,
    unsigned int* __restrict__ dstp,
    int e0, int eb, int m15, int q, int nt4)
{
    f32x4 ca0 = {0.f,0.f,0.f,0.f}, ca1 = {0.f,0.f,0.f,0.f};
    f32x4 cb0 = {0.f,0.f,0.f,0.f}, cb1 = {0.f,0.f,0.f,0.f};
    #pragma unroll
    for (int s = 0; s < 4; ++s) {
        ca0 = __builtin_amdgcn_mfma_f32_16x16x32_bf16(BA[s], A0[s], ca0, 0, 0, 0);
        ca1 = __builtin_amdgcn_mfma_f32_16x16x32_bf16(BA[s], A1[s], ca1, 0, 0, 0);
        cb0 = __builtin_amdgcn_mfma_f32_16x16x32_bf16(BB[s], A0[s], cb0, 0, 0, 0);
        cb1 = __builtin_amdgcn_mfma_f32_16x16x32_bf16(BB[s], A1[s], cb1, 0, 0, 0);
    }
    uint4 U0, U1;
    U0.x = (unsigned int)f2bf(ca0[0]) | ((unsigned int)f2bf(cb0[0]) << 16);
    U0.y = (unsigned int)f2bf(ca0[1]) | ((unsigned int)f2bf(cb0[1]) << 16);
    U0.z = (unsigned int)f2bf(ca0[2]) | ((unsigned int)f2bf(cb0[2]) << 16);
    U0.w = (unsigned int)f2bf(ca0[3]) | ((unsigned int)f2bf(cb0[3]) << 16);
    U1.x = (unsigned int)f2bf(ca1[0]) | ((unsigned int)f2bf(cb1[0]) << 16);
    U1.y = (unsigned int)f2bf(ca1[1]) | ((unsigned int)f2bf(cb1[1]) << 16);
    U1.z = (unsigned int)f2bf(ca1[2]) | ((unsigned int)f2bf(cb1[2]) << 16);
    U1.w = (unsigned int)f2bf(ca1[3]) | ((unsigned int)f2bf(cb1[3]) << 16);
    *(uint4*)(dstp + (size_t)(e0 + eb      + m15)*64 + nt4*16 + q*4) = U0;
    *(uint4*)(dstp + (size_t)(e0 + eb + 16 + m15)*64 + nt4*16 + q*4) = U1;
}

__global__ __launch_bounds__(256, 4) void k_mid(
    const int* __restrict__ esrc, const int* __restrict__ edst,
    const float4* __restrict__ eattr4, const float* __restrict__ elen,
    int* __restrict__ cursor, int* __restrict__ esrc_s,
    int* __restrict__ eidx_s, float4* __restrict__ eattrs,
    const unsigned short* __restrict__ w1t,
    const unsigned short* __restrict__ w2t,
    unsigned int* __restrict__ ewAB,
    unsigned int* __restrict__ ewCD)
{
    __shared__ unsigned short Hs[128 * 136];   // [edge][hid] stride 136

    if (blockIdx.x < N_EDGES / 256) {
        // ---------------- scatter branch -----------------------------------
        const int e = blockIdx.x * 256 + threadIdx.x;
        const int p = atomicAdd(&cursor[edst[e]], 1);
        esrc_s[p] = esrc[e];
        eidx_s[p] = e;
        eattrs[p] = eattr4[e];
        return;
    }

    // ---------------- MLP branch (unsorted edges) --------------------------
    const int t    = threadIdx.x;
    const int w    = t >> 6;
    const int lane = t & 63;
    const int m15  = lane & 15;
    const int q    = lane >> 4;
    const int eb   = w * 32;
    const int e0   = (blockIdx.x - N_EDGES / 256) * 128;

    short8 xa0 = ld_elen8(elen, e0 + eb      + m15, q);
    short8 xa1 = ld_elen8(elen, e0 + eb + 16 + m15, q);

    short8 bw[7];
    #pragma unroll
    for (int nt = 0; nt < 7; ++nt)
        bw[nt] = *(const short8*)(w1t + (nt*16 + m15)*32 + q*8);

    short8 Ba[4], Bb[4], Ca[4], Cb[4];
    p2_ldB(w2t, 0 /*ntA(idx=0)*/, m15, q, Ba, Bb);

    {   // zero hid 112..127 of all 32 rows of this wave
        const int r = eb + (lane >> 1);
        const int c = 112 + (lane & 1) * 8;
        short8 z = {0,0,0,0,0,0,0,0};
        *(short8*)&Hs[r*136 + c] = z;
    }

    // ---- phase 1: D[hid][edge]; lane owns hid nt*16+q*4+{0..3} of edge m15
    #pragma unroll
    for (int nt = 0; nt < 7; ++nt) {
        f32x4 z4 = {0.f, 0.f, 0.f, 0.f};
        f32x4 h0 = __builtin_amdgcn_mfma_f32_16x16x32_bf16(bw[nt], xa0, z4, 0, 0, 0);
        f32x4 h1 = __builtin_amdgcn_mfma_f32_16x16x32_bf16(bw[nt], xa1, z4, 0, 0, 0);
        uint2 d0, d1;
        d0.x = (unsigned int)f2bf(silu_f(h0[0])) | ((unsigned int)f2bf(silu_f(h0[1])) << 16);
        d0.y = (unsigned int)f2bf(silu_f(h0[2])) | ((unsigned int)f2bf(silu_f(h0[3])) << 16);
        d1.x = (unsigned int)f2bf(silu_f(h1[0])) | ((unsigned int)f2bf(silu_f(h1[1])) << 16);
        d1.y = (unsigned int)f2bf(silu_f(h1[2])) | ((unsigned int)f2bf(silu_f(h1[3])) << 16);
        *(uint2*)&Hs[(eb      + m15)*136 + nt*16 + q*4] = d0;
        *(uint2*)&Hs[(eb + 16 + m15)*136 + nt*16 + q*4] = d1;
    }
    // same-wave RAW on Hs -> compiler lgkmcnt, no barrier

    short8 A0[4], A1[4];   // H frags: lane -> (edge m15, k = s*32+q*8+j)
    #pragma unroll
    for (int s = 0; s < 4; ++s) {
        A0[s] = *(const short8*)&Hs[(eb      + m15)*136 + s*32 + q*8];
        A1[s] = *(const short8*)&Hs[(eb + 16 + m15)*136 + s*32 + q*8];
    }

    // ---- phase 2, pipelined: idx = 0..7; grp = idx>>2, nt4 = idx&3,
    // ntA = grp*8 + nt4, dst = grp ? ewCD : ewAB.
    #pragma unroll
    for (int ii = 0; ii < 4; ++ii) {
        const int i0 = 2*ii, i1 = 2*ii + 1;
        const int ntA1 = ((i1 >> 2) * 8) + (i1 & 3);
        p2_ldB(w2t, ntA1, m15, q, Ca, Cb);                     // prefetch odd
        {
            unsigned int* dst0 = (i0 >> 2) ? ewCD : ewAB;
            p2_mfma_store(A0, A1, Ba, Bb, dst0, e0, eb, m15, q, i0 & 3);
        }
        if (ii < 3) {
            const int i2 = i0 + 2;
            const int ntA2 = ((i2 >> 2) * 8) + (i2 & 3);
            p2_ldB(w2t, ntA2, m15, q, Ba, Bb);                 // prefetch next even
        }
        {
            unsigned int* dst1 = (i1 >> 2) ? ewCD : ewAB;
            p2_mfma_store(A0, A1, Ca, Cb, dst1, e0, eb, m15, q, i1 & 3);
        }
    }
}

// ---------------- per-dst gather + fused W_lo GEMM + epilogue ---------------
__global__ __launch_bounds__(256) void k_gather(
    const int* __restrict__ starts, const int* __restrict__ esrc_s,
    const int* __restrict__ eidx_s,
    const float4* __restrict__ eattrs,
    const unsigned int* __restrict__ ewAB,
    const unsigned int* __restrict__ ewCD,
    const ushort4* __restrict__ fvb,
    const float* __restrict__ attr, const float* __restrict__ deg,
    const float* __restrict__ Wlo0, const float* __restrict__ Wlo1,
    float* __restrict__ out)
{
    __shared__ float sm[4][512];
    const int wave = threadIdx.x >> 6;
    const int lane = threadIdx.x & 63;
    const int n = blockIdx.x * 4 + wave;

    const int beg = starts[n], end = starts[n + 1];
    float sA=0.f, sB=0.f;
    float vA0=0.f, vA1=0.f, vA2=0.f;
    float vB0=0.f, vB1=0.f, vB2=0.f;

    for (int base = beg; base < end; base += 64) {
        const int cnt = min(64, end - base);
        int    srcv = 0, eidxv = 0;
        float4 eav  = make_float4(0.f, 0.f, 0.f, 0.f);
        if (lane < cnt) {
            srcv  = esrc_s[base + lane];
            eidxv = eidx_s[base + lane];
            eav   = eattrs[base + lane];
        }
        #pragma unroll 2
        for (int j = 0; j < cnt; ++j) {
            const int   src = __shfl(srcv, j);
            const int   ei  = __shfl(eidxv, j);
            const float y0  = __shfl(eav.x, j);
            const float y10 = __shfl(eav.y, j);
            const float y11 = __shfl(eav.z, j);
            const float y12 = __shfl(eav.w, j);

            const unsigned int uab = ewAB[(size_t)ei*64 + lane];
            const unsigned int ucd = ewCD[(size_t)ei*64 + lane];
            const float wa = bf2f((unsigned short)(uab & 0xFFFFu));
            const float wb = bf2f((unsigned short)(uab >> 16));
            const float wc = bf2f((unsigned short)(ucd & 0xFFFFu));
            const float wd = bf2f((unsigned short)(ucd >> 16));

            const ushort4 g4 = fvb[(size_t)src * 64 + lane];
            const float g0  = bf2f(g4.x);
            const float g10 = bf2f(g4.y);
            const float g11 = bf2f(g4.z);
            const float g12 = bf2f(g4.w);

            const float dotv = g10*y10 + g11*y11 + g12*y12;
            sA += wa * g0 * y0;
            sB += wb * dotv;
            const float t0 = wc * g0;
            vA0 += t0 * y10;  vA1 += t0 * y11;  vA2 += t0 * y12;
            const float t1 = wd * y0;
            vB0 += t1 * g10;  vB1 += t1 * g11;  vB2 += t1 * g12;
        }
    }

    const float dis = 1.0f / sqrtf(deg[n]);
    sm[wave][lane            ] = sA * dis;
    sm[wave][64  + lane      ] = sB * IS3 * dis;
    sm[wave][128 + lane      ] = vA0 * dis;
    sm[wave][128 + 64 + lane ] = vB0 * dis;
    sm[wave][256 + lane      ] = vA1 * dis;
    sm[wave][256 + 64 + lane ] = vB1 * dis;
    sm[wave][384 + lane      ] = vA2 * dis;
    sm[wave][384 + 64 + lane ] = vB2 * dis;
    __syncthreads();

    float o0=0.f, o1x=0.f, o1y=0.f, o1z=0.f;
    #pragma unroll 4
    for (int c = 0; c < 128; ++c) {
        const float w0 = Wlo0[c*64 + lane];
        const float w1 = Wlo1[c*64 + lane];
        o0  += sm[wave][c]         * w0;
        o1x += sm[wave][128 + c]   * w1;
        o1y += sm[wave][256 + c]   * w1;
        o1z += sm[wave][384 + c]   * w1;
    }

    const float a = attr[n] * INVLO;
    float* orow = out + (size_t)n * 256;
    orow[lane] += C_X * o0 * a;
    orow[64 + lane*3    ] += C_X * o1x * a;
    orow[64 + lane*3 + 1] += C_X * o1y * a;
    orow[64 + lane*3 + 2] += C_X * o1z * a;
}

// ======================= fallback (round-1) path ============================
__global__ __launch_bounds__(256) void k_node_in_legacy(
    const float* __restrict__ ni, const float* __restrict__ attr,
    const float* __restrict__ deg,
    const float* __restrict__ Wli0, const float* __restrict__ Wli1,
    const float* __restrict__ Wlm0, const float* __restrict__ Wlm1,
    float* __restrict__ f, float* __restrict__ out)
{
    __shared__ float raw[4][256];
    const int wave = threadIdx.x >> 6;
    const int lane = threadIdx.x & 63;
    const int n = blockIdx.x * 4 + wave;

    const float* row = ni + (size_t)n * 256;
    raw[wave][lane      ] = row[lane      ];
    raw[wave][lane + 64 ] = row[lane + 64 ];
    raw[wave][lane + 128] = row[lane + 128];
    raw[wave][lane + 192] = row[lane + 192];
    __syncthreads();

    float f0 = 0.f, m0 = 0.f;
    float f1x = 0.f, f1y = 0.f, f1z = 0.f;
    float m1x = 0.f, m1y = 0.f, m1z = 0.f;
    for (int t = 0; t < 64; ++t) {
        float xs  = raw[wave][t];
        float xv0 = raw[wave][64 + t*3    ];
        float xv1 = raw[wave][64 + t*3 + 1];
        float xv2 = raw[wave][64 + t*3 + 2];
        float a0 = Wli0[t*64 + lane];
        float a1 = Wli1[t*64 + lane];
        float b0 = Wlm0[t*64 + lane];
        float b1 = Wlm1[t*64 + lane];
        f0  += xs  * a0;   m0  += xs  * b0;
        f1x += xv0 * a1;   f1y += xv1 * a1;   f1z += xv2 * a1;
        m1x += xv0 * b1;   m1y += xv1 * b1;   m1z += xv2 * b1;
    }

    const float a   = attr[n] * INV64;
    const float dis = 1.0f / sqrtf(deg[n]);
    const float fa  = a * dis;

    float* fr = f + (size_t)n * 256;
    fr[lane      ] = f0  * fa;
    fr[64  + lane] = f1x * fa;
    fr[128 + lane] = f1y * fa;
    fr[192 + lane] = f1z * fa;

    float* orow = out + (size_t)n * 256;
    orow[lane] = C_S * m0 * a;
    orow[64 + lane*3    ] = C_S * m1x * a;
    orow[64 + lane*3 + 1] = C_S * m1y * a;
    orow[64 + lane*3 + 2] = C_S * m1z * a;
}

__global__ __launch_bounds__(256) void k_edge_legacy(
    const float* __restrict__ eattr, const float* __restrict__ elen,
    const float* __restrict__ W1, const float* __restrict__ W2,
    const int* __restrict__ esrc, const int* __restrict__ edst,
    const float* __restrict__ f, float* __restrict__ acc)
{
    __shared__ float hsh[4][104];
    const int wave = threadIdx.x >> 6;
    const int lane = threadIdx.x & 63;
    const int e = blockIdx.x * 4 + wave;

    const float* el = elen + (size_t)e * 10;
    float elr[10];
    #pragma unroll
    for (int b = 0; b < 10; ++b) elr[b] = el[b];

    float a1 = 0.f;
    #pragma unroll
    for (int b = 0; b < 10; ++b) a1 += elr[b] * W1[b*100 + lane];
    hsh[wave][lane] = silu_f(a1 * INV1);
    if (lane < 36) {
        float a2 = 0.f;
        #pragma unroll
        for (int b = 0; b < 10; ++b) a2 += elr[b] * W1[b*100 + 64 + lane];
        hsh[wave][64 + lane] = silu_f(a2 * INV1);
    }
    __syncthreads();

    float wa = 0.f, wb = 0.f, wc = 0.f, wd = 0.f;
    for (int j = 0; j < 100; ++j) {
        float hj = hsh[wave][j];
        const float* wr = W2 + j*256;
        wa += hj * wr[lane      ];
        wb += hj * wr[64  + lane];
        wc += hj * wr[128 + lane];
        wd += hj * wr[192 + lane];
    }
    wa *= SC2; wb *= SC2; wc *= SC2; wd *= SC2;

    const int src = esrc[e];
    const int dst = edst[e];
    const float y0  = eattr[e*4 + 0];
    const float y10 = eattr[e*4 + 1];
    const float y11 = eattr[e*4 + 2];
    const float y12 = eattr[e*4 + 3];

    const float* fr = f + (size_t)src * 256;
    const float g0  = fr[lane      ];
    const float g10 = fr[64  + lane];
    const float g11 = fr[128 + lane];
    const float g12 = fr[192 + lane];

    const float dotv = g10*y10 + g11*y11 + g12*y12;

    float* ar = acc + (size_t)dst * 512;
    atomicAdd(ar + lane,                  wa * g0 * y0);
    atomicAdd(ar + 64 + lane,             wb * dotv * IS3);
    atomicAdd(ar + 128 +   0 + lane,      wc * g0 * y10);
    atomicAdd(ar + 128 + 128 + lane,      wc * g0 * y11);
    atomicAdd(ar + 128 + 256 + lane,      wc * g0 * y12);
    atomicAdd(ar + 128 +   0 + 64 + lane, wd * g10 * y0);
    atomicAdd(ar + 128 + 128 + 64 + lane, wd * g11 * y0);
    atomicAdd(ar + 128 + 256 + 64 + lane, wd * g12 * y0);
}

__global__ __launch_bounds__(256) void k_node_out_legacy(
    const float* __restrict__ acc, const float* __restrict__ attr,
    const float* __restrict__ deg, const float* __restrict__ Wlo0,
    const float* __restrict__ Wlo1, float* __restrict__ out)
{
    __shared__ float sm[4][512];
    const int wave = threadIdx.x >> 6;
    const int lane = threadIdx.x & 63;
    const int n = blockIdx.x * 4 + wave;

    const float dis = 1.0f / sqrtf(deg[n]);
    const float* ar = acc + (size_t)n * 512;
    for (int i = lane; i < 512; i += 64) sm[wave][i] = ar[i] * dis;
    __syncthreads();

    float o0 = 0.f, o1x = 0.f, o1y = 0.f, o1z = 0.f;
    for (int c = 0; c < 128; ++c) {
        float w0 = Wlo0[c*64 + lane];
        float w1 = Wlo1[c*64 + lane];
        o0  += sm[wave][c]        * w0;
        o1x += sm[wave][128 + c]  * w1;
        o1y += sm[wave][256 + c]  * w1;
        o1z += sm[wave][384 + c]  * w1;
    }

    const float a = attr[n] * INVLO;
    float* orow = out + (size_t)n * 256;
    orow[lane] += C_X * o0 * a;
    orow[64 + lane*3    ] += C_X * o1x * a;
    orow[64 + lane*3 + 1] += C_X * o1y * a;
    orow[64 + lane*3 + 2] += C_X * o1z * a;
}

// ============================================================================
extern "C" void kernel_launch(void* const* d_in, const int* in_sizes, int n_in,
                              void* d_out, int out_size, void* d_ws, size_t ws_size,
                              hipStream_t stream) {
    const float* ni    = (const float*)d_in[0];
    const float* attr  = (const float*)d_in[1];
    const float* deg   = (const float*)d_in[2];
    const float* eattr = (const float*)d_in[3];
    const float* elen  = (const float*)d_in[4];
    const float* Wli0  = (const float*)d_in[5];
    const float* Wli1  = (const float*)d_in[6];
    const float* Wlm0  = (const float*)d_in[7];
    const float* Wlm1  = (const float*)d_in[8];
    const float* Wm1   = (const float*)d_in[9];
    const float* Wm2   = (const float*)d_in[10];
    const float* Wlo0  = (const float*)d_in[11];
    const float* Wlo1  = (const float*)d_in[12];
    const int*   esrc  = (const int*)d_in[13];
    const int*   edst  = (const int*)d_in[14];

    float* out = (float*)d_out;

    // ws layout (fast path), 16 B-aligned sections
    char* wsb = (char*)d_ws;
    size_t off = 0;
    ushort4* fvb = (ushort4*)(wsb + off);               off += (size_t)N_NODES * 64 * 8;    // 10.24 MB
    unsigned int* ewAB = (unsigned int*)(wsb + off);    off += (size_t)N_EDGES * 64 * 4;    // 81.92 MB
    unsigned int* ewCD = (unsigned int*)(wsb + off);    off += (size_t)N_EDGES * 64 * 4;    // 81.92 MB
    float4* eattrs = (float4*)(wsb + off);              off += (size_t)N_EDGES * 16;        // 5.12 MB
    int* esrc_s = (int*)(wsb + off);                    off += (size_t)N_EDGES * 4;         // 1.28 MB
    int* eidx_s = (int*)(wsb + off);                    off += (size_t)N_EDGES * 4;         // 1.28 MB
    unsigned short* w2t = (unsigned short*)(wsb + off); off += 32768 * 2;
    unsigned short* w1t = (unsigned short*)(wsb + off); off += 3584 * 2;
    int* starts = (int*)(wsb + off);                    off += (size_t)(N_NODES + 4) * 4;
    int* hist   = (int*)(wsb + off);                    off += (size_t)N_NODES * 4;
    int* cursor = (int*)(wsb + off);                    off += (size_t)N_NODES * 4;
    const size_t need_fast = off;

    if (ws_size >= need_fast) {
        hipMemsetAsync(hist, 0, (size_t)N_NODES * sizeof(int), stream);
        k_pre    <<<N_NODES / 8 + N_EDGES / 256 + 144, 256, 0, stream>>>(
                     ni, attr, deg, Wli0, Wli1, Wlm0, Wlm1, fvb, out,
                     edst, hist, Wm2, Wm1, w2t, w1t);
        k_scan   <<<1, 1024, 0, stream>>>(hist, starts, cursor);
        k_mid    <<<N_EDGES / 256 + N_EDGES / 128, 256, 0, stream>>>(
                     esrc, edst, (const float4*)eattr, elen,
                     cursor, esrc_s, eidx_s, eattrs,
                     w1t, w2t, ewAB, ewCD);
        k_gather <<<N_NODES / 4, 256, 0, stream>>>(starts, esrc_s, eidx_s,
                                                   eattrs, ewAB, ewCD,
                                                   fvb, attr, deg,
                                                   Wlo0, Wlo1, out);
    } else {
        // fallback: round-1 atomic path (61.4 MB scratch)
        float* f   = (float*)d_ws;
        float* acc = f + (size_t)N_NODES * 256;
        hipMemsetAsync(acc, 0, (size_t)N_NODES * 512 * sizeof(float), stream);
        k_node_in_legacy<<<N_NODES / 4, 256, 0, stream>>>(ni, attr, deg, Wli0, Wli1,
                                                          Wlm0, Wlm1, f, out);
        k_edge_legacy<<<N_EDGES / 4, 256, 0, stream>>>(eattr, elen, Wm1, Wm2,
                                                       esrc, edst, f, acc);
        k_node_out_legacy<<<N_NODES / 4, 256, 0, stream>>>(acc, attr, deg,
                                                           Wlo0, Wlo1, out);
    }
}